// Round 14
// baseline (779.987 us; speedup 1.0000x reference)
//
#include <hip/hip_runtime.h>
#include <hip/hip_bf16.h>
#include <cstdint>

using short8  = __attribute__((ext_vector_type(8))) short;
using ushort8 = __attribute__((ext_vector_type(8))) unsigned short;
using short4v = __attribute__((ext_vector_type(4))) short;
using f32x4   = __attribute__((ext_vector_type(4))) float;

#define H_    8
#define SLEN  1024
#define BSZ   32
#define INDIM 512
#define NQKV  1544   // H*(3*D+1)
#define NPAD2 1792   // 7*256 (gemm_qkv N padding)
#define MROWS 32768  // SLEN*BSZ
#define PB    72     // bf16 LDS pad stride

#define GLOAD16(gp, lp) __builtin_amdgcn_global_load_lds( \
    (const __attribute__((address_space(1))) void*)(gp),  \
    (__attribute__((address_space(3))) void*)(lp), 16, 0, 0)

#define VMCNT4() do { asm volatile("s_waitcnt vmcnt(4)" ::: "memory"); \
                      __builtin_amdgcn_sched_barrier(0); } while (0)
#define VMCNT0() do { asm volatile("s_waitcnt vmcnt(0)" ::: "memory"); \
                      __builtin_amdgcn_sched_barrier(0); } while (0)
#define SBAR()   do { __builtin_amdgcn_sched_barrier(0); \
                      __builtin_amdgcn_s_barrier(); \
                      __builtin_amdgcn_sched_barrier(0); } while (0)

static __device__ __forceinline__ float bf2f(unsigned short s) {
    return __uint_as_float(((unsigned int)s) << 16);
}
static __device__ __forceinline__ unsigned short f2bf(float f) {
    union { __hip_bfloat16 b; unsigned short u; } cv;
    cv.b = __float2bfloat16(f);    // HW RNE on gfx950, bit-identical to manual RNE
    return cv.u;
}

// ---------------- LayerNorm: x[32768][512] f32 -> h bf16 ----------------
__global__ __launch_bounds__(256) void ln_kernel(const float* __restrict__ x,
                                                 const float* __restrict__ gamma,
                                                 const float* __restrict__ betap,
                                                 unsigned short* __restrict__ h) {
    int row = blockIdx.x * 4 + (threadIdx.x >> 6);
    int l   = threadIdx.x & 63;
    const f32x4* xr = (const f32x4*)(x + (size_t)row * INDIM);
    f32x4 a = xr[l * 2], b = xr[l * 2 + 1];
    float s = 0.f, sq = 0.f;
    #pragma unroll
    for (int j = 0; j < 4; ++j) { s += a[j]; sq += a[j] * a[j]; }
    #pragma unroll
    for (int j = 0; j < 4; ++j) { s += b[j]; sq += b[j] * b[j]; }
    #pragma unroll
    for (int off = 32; off; off >>= 1) { s += __shfl_xor(s, off); sq += __shfl_xor(sq, off); }
    float mean = s * (1.f / 512.f);
    float var  = sq * (1.f / 512.f) - mean * mean;
    float rstd = rsqrtf(var + 1e-5f);
    const f32x4* g4 = (const f32x4*)gamma;
    const f32x4* b4 = (const f32x4*)betap;
    f32x4 g0 = g4[l * 2], g1 = g4[l * 2 + 1], e0 = b4[l * 2], e1 = b4[l * 2 + 1];
    short8 o;
    #pragma unroll
    for (int j = 0; j < 4; ++j) o[j]     = (short)f2bf((a[j] - mean) * rstd * g0[j] + e0[j]);
    #pragma unroll
    for (int j = 0; j < 4; ++j) o[4 + j] = (short)f2bf((b[j] - mean) * rstd * g1[j] + e1[j]);
    ((short8*)(h + (size_t)row * INDIM))[l] = o;
}

// ---------------- weight transpose+permute via LDS tiles (coalesced both sides) ----------------
__global__ __launch_bounds__(256) void cvt_wslow2(const float* __restrict__ w,
                                                  unsigned short* __restrict__ wT) {
    __shared__ float T[64][65];
    const int tid = threadIdx.x;
    const int k0 = blockIdx.x * 64;
    const int ng = blockIdx.y;                 // 0..24
    if (ng < 24) {
        const int cbase = (ng & 7) * 193 + (ng >> 3) * 64;   // q:+0 k:+64 v:+128
        const int nn = tid & 63, kk = tid >> 6;
        #pragma unroll
        for (int i = 0; i < 16; ++i)
            T[kk + 4 * i][nn] = w[(size_t)(k0 + kk + 4 * i) * NQKV + cbase + nn];
        __syncthreads();
        const int kseg = (tid & 7) * 8;
        #pragma unroll
        for (int i = 0; i < 2; ++i) {
            int nn2 = i * 32 + (tid >> 3);
            ushort8 o;
            #pragma unroll
            for (int j = 0; j < 8; ++j) o[j] = f2bf(T[kseg + j][nn2]);
            *(ushort8*)&wT[(size_t)(ng * 64 + nn2) * 512 + k0 + kseg] = o;
        }
    } else {
        for (int i = 0; i < 64; ++i) {
            int gid = i * 256 + tid;
            int nn = gid >> 6, kk = gid & 63;
            int n = 1536 + nn;
            unsigned short v = 0;
            if (n < 1544) v = f2bf(w[(size_t)(k0 + kk) * NQKV + (n - 1536) * 193 + 192]);
            wT[(size_t)n * 512 + k0 + kk] = v;
        }
    }
}
__global__ __launch_bounds__(256) void cvt_wout(const float* __restrict__ w,
                                                unsigned short* __restrict__ wT) {
    __shared__ float T[64][65];
    const int tid = threadIdx.x;
    const int k0 = blockIdx.x * 64;
    const int n0 = blockIdx.y * 64;
    const int nn = tid & 63, kk = tid >> 6;
    #pragma unroll
    for (int i = 0; i < 16; ++i)
        T[kk + 4 * i][nn] = w[(size_t)(k0 + kk + 4 * i) * 512 + n0 + nn];
    __syncthreads();
    const int kseg = (tid & 7) * 8;
    #pragma unroll
    for (int i = 0; i < 2; ++i) {
        int nn2 = i * 32 + (tid >> 3);
        ushort8 o;
        #pragma unroll
        for (int j = 0; j < 8; ++j) o[j] = f2bf(T[kseg + j][nn2]);
        *(ushort8*)&wT[(size_t)(n0 + nn2) * 512 + k0 + kseg] = o;
    }
}

// ---------------- GEMM1 fused, 256x256 tile, BK=32, 64KB LDS (2 blocks/CU), counted-vmcnt ----------------
__global__ __launch_bounds__(512, 4) void gemm_qkv(const unsigned short* __restrict__ A,
                                                   const unsigned short* __restrict__ BT,
                                                   unsigned short* __restrict__ qn,
                                                   unsigned short* __restrict__ kn,
                                                   unsigned short* __restrict__ vn,
                                                   float* __restrict__ bet) {
    __shared__ unsigned short SMEM[32768];            // 64 KB: A dbuf [0,16384), B dbuf [16384,32768)
    const int tid = threadIdx.x;
    const int id = blockIdx.y * 7 + blockIdx.x;       // 896 = 8*112
    const int newid = (id & 7) * 112 + (id >> 3);     // bijective XCD chunking
    const int bx = newid % 7;
    const int n0 = bx * 256;
    const int m0 = (newid / 7) * 256;
    const int w = tid >> 6, l = tid & 63;
    const int wm = w >> 2, wn = w & 3;
    const int lr = l & 15, lk8 = (l >> 4) * 8;
    f32x4 acc[8][4] = {};

    auto STAGE = [&](int buf, int kt) {
        #pragma unroll
        for (int c2 = 0; c2 < 2; ++c2) {
            int idx = c2 * 512 + tid;
            int row = idx >> 2, kc2 = (idx & 3) * 8;
            int lb = (c2 * 512 + (tid & 448)) * 8;    // wave-uniform base; lane offset = (tid&63)*16B
            GLOAD16(A  + (size_t)(m0 + row) * INDIM + kt + kc2, &SMEM[buf * 8192 + lb]);
            GLOAD16(BT + (size_t)(n0 + row) * INDIM + kt + kc2, &SMEM[16384 + buf * 8192 + lb]);
        }
    };
    auto COMPUTE = [&](int buf) {
        const unsigned short* As = &SMEM[buf * 8192];
        const unsigned short* Bs = &SMEM[16384 + buf * 8192];
        short8 bf2[4];
        #pragma unroll
        for (int ni = 0; ni < 4; ++ni)
            bf2[ni] = *(const short8*)&Bs[(wn * 64 + ni * 16 + lr) * 32 + lk8];
        #pragma unroll
        for (int p = 0; p < 4; ++p) {
            short8 af[2];
            #pragma unroll
            for (int d = 0; d < 2; ++d)
                af[d] = *(const short8*)&As[(wm * 128 + (2 * p + d) * 16 + lr) * 32 + lk8];
            #pragma unroll
            for (int d = 0; d < 2; ++d)
                #pragma unroll
                for (int ni = 0; ni < 4; ++ni)
                    acc[2 * p + d][ni] =
                        __builtin_amdgcn_mfma_f32_16x16x32_bf16(af[d], bf2[ni], acc[2 * p + d][ni], 0, 0, 0);
        }
    };

    STAGE(0, 0);
    STAGE(1, 32);
    #pragma unroll
    for (int t = 0; t < 16; ++t) {
        if (t == 15) { VMCNT0(); } else { VMCNT4(); }   // tile t landed
        SBAR();
        COMPUTE(t & 1);
        SBAR();                                          // buf freed
        if (t + 2 < 16) STAGE(t & 1, (t + 2) * 32);
    }

    // ---- fused epilogue: two 128-row halves staged through the 64KB SMEM ----
    const int g = l >> 4, cc = l & 15;
    const int colbase = n0 + wn * 64;
    if (bx < 6) {
        const int reg = colbase >> 9;                    // 0=q,1=k,2=v (block-uniform)
        unsigned short* dst = (reg == 0) ? qn : (reg == 1) ? kn : vn;
        #pragma unroll
        for (int hp = 0; hp < 2; ++hp) {
            SBAR();
            if (wm == hp) {
                #pragma unroll
                for (int mi = 0; mi < 8; ++mi) {
                    #pragma unroll
                    for (int j = 0; j < 4; ++j) {
                        float e0 = acc[mi][0][j], e1 = acc[mi][1][j], e2 = acc[mi][2][j], e3 = acc[mi][3][j];
                        if (reg < 2) {
                            e0 = e0 > 0.f ? e0 + 1.f : __expf(e0);
                            e1 = e1 > 0.f ? e1 + 1.f : __expf(e1);
                            e2 = e2 > 0.f ? e2 + 1.f : __expf(e2);
                            e3 = e3 > 0.f ? e3 + 1.f : __expf(e3);
                            float ssum = (e0 + e1) + (e2 + e3);
                            ssum += __shfl_xor(ssum, 1);
                            ssum += __shfl_xor(ssum, 2);
                            ssum += __shfl_xor(ssum, 4);
                            ssum += __shfl_xor(ssum, 8);
                            float inv = 1.f / ssum;
                            e0 *= inv; e1 *= inv; e2 *= inv; e3 *= inv;
                        }
                        int lrow = mi * 16 + g * 4 + j;          // 0..127 within half
                        int key = ((lrow >> 2) & 3) << 4;
                        int cb = wn * 64;
                        SMEM[lrow * 256 + ((cb +  0 + cc) ^ key)] = f2bf(e0);
                        SMEM[lrow * 256 + ((cb + 16 + cc) ^ key)] = f2bf(e1);
                        SMEM[lrow * 256 + ((cb + 32 + cc) ^ key)] = f2bf(e2);
                        SMEM[lrow * 256 + ((cb + 48 + cc) ^ key)] = f2bf(e3);
                    }
                }
            }
            SBAR();
            #pragma unroll
            for (int it = 0; it < 8; ++it) {
                int idx = it * 512 + tid;
                int lrow = idx >> 5, seg = idx & 31;
                int key = ((lrow >> 2) & 3) << 4;
                ushort8 v = *(const ushort8*)&SMEM[lrow * 256 + ((seg * 8) ^ key)];
                int grow = m0 + hp * 128 + lrow;
                int s = grow >> 5, b = grow & 31;
                int gcol = n0 + seg * 8;
                int hd = (gcol >> 6) & 7, d0 = gcol & 63;
                *(ushort8*)(dst + ((size_t)(b * H_ + hd) * SLEN + s) * 64 + d0) = v;
            }
        }
    } else {
        // bx==6: beta cols 1536..1543 live in strip wn==0, frag ni=0, cc<8; rest is pad
        if (wn == 0 && cc < 8) {
            #pragma unroll
            for (int mi = 0; mi < 8; ++mi)
                #pragma unroll
                for (int j = 0; j < 4; ++j) {
                    int row = m0 + wm * 128 + mi * 16 + g * 4 + j;
                    int s = row >> 5, b = row & 31;
                    float v = acc[mi][0][j];
                    bet[(size_t)(b * H_ + cc) * SLEN + s] = 1.f / (1.f + __expf(-v));
                }
        }
    }
}

// ---------------- GEMM2, 256x256 tile, BK=32, 64KB LDS: out = x + outs @ woT^T ----------------
__global__ __launch_bounds__(512, 4) void gemm_out(const unsigned short* __restrict__ A,
                                                   const unsigned short* __restrict__ BT,
                                                   const float* __restrict__ X,
                                                   float* __restrict__ outf) {
    __shared__ unsigned short As2[2][8192];
    __shared__ unsigned short Bs2[2][8192];
    const int tid = threadIdx.x;
    const int id = blockIdx.y * 2 + blockIdx.x;       // 256 = 8*32
    const int newid = (id & 7) * 32 + (id >> 3);
    const int n0 = (newid & 1) * 256;
    const int m0 = (newid >> 1) * 256;
    const int w = tid >> 6, l = tid & 63;
    const int wm = w >> 2, wn = w & 3;
    const int lr = l & 15, lk8 = (l >> 4) * 8;
    f32x4 acc[8][4] = {};

    auto STAGE = [&](int buf, int kt) {
        #pragma unroll
        for (int c2 = 0; c2 < 2; ++c2) {
            int idx = c2 * 512 + tid;
            int row = idx >> 2, kc2 = (idx & 3) * 8;
            int lb = (c2 * 512 + (tid & 448)) * 8;
            GLOAD16(A  + (size_t)(m0 + row) * INDIM + kt + kc2, &As2[buf][lb]);
            GLOAD16(BT + (size_t)(n0 + row) * INDIM + kt + kc2, &Bs2[buf][lb]);
        }
    };
    auto COMPUTE = [&](int buf) {
        short8 bf2[4];
        #pragma unroll
        for (int ni = 0; ni < 4; ++ni)
            bf2[ni] = *(const short8*)&Bs2[buf][(wn * 64 + ni * 16 + lr) * 32 + lk8];
        #pragma unroll
        for (int p = 0; p < 4; ++p) {
            short8 af[2];
            #pragma unroll
            for (int d = 0; d < 2; ++d)
                af[d] = *(const short8*)&As2[buf][(wm * 128 + (2 * p + d) * 16 + lr) * 32 + lk8];
            #pragma unroll
            for (int d = 0; d < 2; ++d)
                #pragma unroll
                for (int ni = 0; ni < 4; ++ni)
                    acc[2 * p + d][ni] =
                        __builtin_amdgcn_mfma_f32_16x16x32_bf16(af[d], bf2[ni], acc[2 * p + d][ni], 0, 0, 0);
        }
    };

    STAGE(0, 0);
    STAGE(1, 32);
    #pragma unroll
    for (int t = 0; t < 16; ++t) {
        if (t == 15) { VMCNT0(); } else { VMCNT4(); }
        SBAR();
        COMPUTE(t & 1);
        SBAR();
        if (t + 2 < 16) STAGE(t & 1, (t + 2) * 32);
    }

    const int g = l >> 4, cc = l & 15;
    #pragma unroll
    for (int mi = 0; mi < 8; ++mi)
        #pragma unroll
        for (int ni = 0; ni < 4; ++ni)
            #pragma unroll
            for (int j = 0; j < 4; ++j) {
                int row = m0 + wm * 128 + mi * 16 + g * 4 + j;
                int col = n0 + wn * 64 + ni * 16 + cc;
                size_t o = (size_t)row * 512 + col;
                outf[o] = X[o] + acc[mi][ni][j];
            }
}

// ---------------- phase 1 v3: per-(bh,chunk) WY tile factors, 8 waves, conflict-fixed ----------------
__global__ __launch_bounds__(512, 4) void fwtiles(const unsigned short* __restrict__ qn,
                                                  const unsigned short* __restrict__ kn,
                                                  const unsigned short* __restrict__ vn,
                                                  const float* __restrict__ beta,
                                                  unsigned short* __restrict__ tiles,
                                                  unsigned short* __restrict__ outs) {
    __shared__ unsigned short Ax[64 * PB], Atr[64 * PB], Pw[64 * PB], Pwtr[64 * PB];
    __shared__ unsigned short Z0[128 * PB], Z1[128 * PB];
    __shared__ float bv[64];
    const int bx = blockIdx.x;
    const int bh = bx >> 4, c = bx & 15;
    const int b = bh >> 3, h = bh & 7;
    const int c0 = c * 64;
    const int tid = threadIdx.x;
    const int w = tid >> 6, l = tid & 63;
    const int mw = w & 3, nh = w >> 2;
    const int lr = l & 15, lk = (l >> 4) << 3, rb = (l >> 4) << 2;
    const unsigned short* kc = kn + ((size_t)bh * SLEN + c0) * 64;
    const unsigned short* qc = qn + ((size_t)bh * SLEN + c0) * 64;
    const unsigned short* vc = vn + ((size_t)bh * SLEN + c0) * 64;
    const float* bb = beta + (size_t)bh * SLEN + c0;

    {
        #pragma unroll
        for (int i = 0; i < 2; ++i) {
            int idx = i * 512 + tid;
            int row = idx >> 3, seg = idx & 7;
            const unsigned short* src = (row < 64) ? (vc + (size_t)row * 64 + seg * 8)
                                                   : (kc + (size_t)(row - 64) * 64 + seg * 8);
            *(ushort8*)&Z1[row * PB + seg * 8] = *(const ushort8*)src;
        }
        if (tid < 64) bv[tid] = bb[tid];
        ushort8 z8 = {};
        for (int i = tid; i < 576; i += 512) { ((ushort8*)Ax)[i] = z8; ((ushort8*)Atr)[i] = z8; }
    }
    __syncthreads();

    auto ldb = [&](const unsigned short* M, int m, int kk) -> short8 {
        return *(const short8*)&M[(m * 16 + lr) * PB + kk * 32 + lk];
    };

    {
        const int zoff2 = (w >> 2) * 64;
        const int tbase = (w & 3) * 16;
        const float sgn = (w >= 4) ? -1.f : 1.f;
        ushort8 b0v, b1v;
        #pragma unroll
        for (int i = 0; i < 16; ++i) {
            int r = w * 16 + i;
            float val = sgn * bv[tbase + i] * bf2f(Z1[r * PB + l]);
            unsigned short uv = f2bf(val);
            if (i < 8) b0v[i] = uv; else b1v[i - 8] = uv;
        }
        *(ushort8*)&Z0[(zoff2 + l) * PB + tbase]     = b0v;
        *(ushort8*)&Z0[(zoff2 + l) * PB + tbase + 8] = b1v;
    }
    {
        const int pm[10] = {0, 1, 1, 2, 2, 2, 3, 3, 3, 3};
        const int pn[10] = {0, 0, 1, 0, 1, 2, 0, 1, 2, 3};
        for (int pi = w; pi < 10; pi += 8) {
            int m = pm[pi], n = pn[pi];
            short8 ka0 = *(const short8*)&Z1[(64 + 16 * m + lr) * PB + lk];
            short8 ka1 = *(const short8*)&Z1[(64 + 16 * m + lr) * PB + 32 + lk];
            short8 kb0 = *(const short8*)&Z1[(64 + 16 * n + lr) * PB + lk];
            short8 kb1 = *(const short8*)&Z1[(64 + 16 * n + lr) * PB + 32 + lk];
            f32x4 a = {};
            a = __builtin_amdgcn_mfma_f32_16x16x32_bf16(ka0, kb0, a, 0, 0, 0);
            a = __builtin_amdgcn_mfma_f32_16x16x32_bf16(ka1, kb1, a, 0, 0, 0);
            f32x4 btm = *(const f32x4*)&bv[16 * m + rb];
            short4v pk;
            #pragma unroll
            for (int j = 0; j < 4; ++j) {
                int tt = 16 * m + rb + j, s = 16 * n + lr;
                unsigned short v = (s < tt) ? f2bf(-btm[j] * a[j]) : (unsigned short)0;
                Ax[tt * PB + s] = v;
                pk[j] = (short)v;
            }
            *(short4v*)&Atr[(16 * n + lr) * PB + 16 * m + rb] = pk;
        }
    }
    __syncthreads();

    auto zprod = [&](const unsigned short* Xb, int p, const unsigned short* Zs, unsigned short* Zd) {
        const bool msk0 = (16 * mw + 15 >= p), msk1 = (16 * mw + 15 - 32 >= p);
        short8 xf0, xf1;
        if (msk0) xf0 = ldb(Xb, mw, 0);
        if (msk1) xf1 = ldb(Xb, mw, 1);
        #pragma unroll
        for (int ni = 0; ni < 4; ++ni) {
            int n = nh * 4 + ni;
            short4v zi = *(const short4v*)&Zs[(16 * n + lr) * PB + 16 * mw + rb];
            f32x4 a;
            #pragma unroll
            for (int j = 0; j < 4; ++j) a[j] = bf2f((unsigned short)zi[j]);
            if (msk0) a = __builtin_amdgcn_mfma_f32_16x16x32_bf16(xf0, ldb(Zs, n, 0), a, 0, 0, 0);
            if (msk1) a = __builtin_amdgcn_mfma_f32_16x16x32_bf16(xf1, ldb(Zs, n, 1), a, 0, 0, 0);
            short4v zo;
            #pragma unroll
            for (int j = 0; j < 4; ++j) zo[j] = (short)f2bf(a[j]);
            *(short4v*)&Zd[(16 * n + lr) * PB + 16 * mw + rb] = zo;
        }
    };
    auto powp = [&](const unsigned short* Ps, const unsigned short* Pstr, int p,
                    unsigned short* Pd, unsigned short* Pdtr, bool wrTr) {
        const bool x0 = (16 * mw + 15 >= p), x1 = (16 * mw + 15 - 32 >= p);
        short8 xf0, xf1;
        if (x0) xf0 = ldb(Ps, mw, 0);
        if (x1) xf1 = ldb(Ps, mw, 1);
        #pragma unroll
        for (int ni = 0; ni < 2; ++ni) {
            int n = nh * 2 + ni;
            const bool y0 = (31 - 16 * n >= p), y1 = (63 - 16 * n >= p);
            f32x4 a = {};
            if (x0 && y0) a = __builtin_amdgcn_mfma_f32_16x16x32_bf16(xf0, ldb(Pstr, n, 0), a, 0, 0, 0);
            if (x1 && y1) a = __builtin_amdgcn_mfma_f32_16x16x32_bf16(xf1, ldb(Pstr, n, 1), a, 0, 0, 0);
            short4v pk;
            #pragma unroll
            for (int j = 0; j < 4; ++j) {
                unsigned short v = f2bf(a[j]);
                Pd[(16 * mw + rb + j) * PB + 16 * n + lr] = v;
                pk[j] = (short)v;
            }
            if (wrTr) *(short4v*)&Pdtr[(16 * n + lr) * PB + 16 * mw + rb] = pk;
        }
    };

    zprod(Ax, 1, Z0, Z1);  powp(Ax, Atr, 1, Pw, Pwtr, true);   __syncthreads();
    zprod(Pw, 2, Z1, Z0);  powp(Pw, Pwtr, 2, Ax, Atr, true);   __syncthreads();
    zprod(Ax, 4, Z0, Z1);  powp(Ax, Atr, 4, Pw, Pwtr, true);   __syncthreads();
    zprod(Pw, 8, Z1, Z0);  powp(Pw, Pwtr, 8, Ax, Atr, true);   __syncthreads();
    zprod(Ax, 16, Z0, Z1); powp(Ax, Atr, 16, Pw, Pwtr, false); __syncthreads();
    zprod(Pw, 32, Z1, Z0);
    __syncthreads();

    {
        #pragma unroll
        for (int i = 0; i < 2; ++i) {
            int idx = i * 512 + tid;
            int row = idx >> 3, seg = idx & 7;
            const unsigned short* src = (row < 64) ? (qc + (size_t)row * 64 + seg * 8)
                                                   : (kc + (size_t)(row - 64) * 64 + seg * 8);
            *(ushort8*)&Z1[row * PB + seg * 8] = *(const ushort8*)src;
        }
    }
    __syncthreads();

    {
        short8 qa0 = *(const short8*)&Z1[(16 * mw + lr) * PB + lk];
        short8 qa1 = *(const short8*)&Z1[(16 * mw + lr) * PB + 32 + lk];
        #pragma unroll
        for (int ni = 0; ni < 2; ++ni) {
            int n = nh * 2 + ni;
            short8 kb0 = *(const short8*)&Z1[(64 + 16 * n + lr) * PB + lk];
            short8 kb1 = *(const short8*)&Z1[(64 + 16 * n + lr) * PB + 32 + lk];
            f32x4 a = {};
            a = __builtin_amdgcn_mfma_f32_16x16x32_bf16(qa0, kb0, a, 0, 0, 0);
            a = __builtin_amdgcn_mfma_f32_16x16x32_bf16(qa1, kb1, a, 0, 0, 0);
            #pragma unroll
            for (int j = 0; j < 4; ++j) {
                int tt = 16 * mw + rb + j, s = 16 * n + lr;
                Ax[tt * PB + s] = (s <= tt) ? f2bf(a[j]) : (unsigned short)0;
            }
        }
        ushort8 kv;
        #pragma unroll
        for (int j = 0; j < 8; ++j)
            kv[j] = Z1[(64 + w * 8 + j) * PB + l];
        *(ushort8*)&Pwtr[l * PB + w * 8] = kv;
    }
    __syncthreads();

    {
        unsigned short* tb = tiles + ((size_t)bh * 16 + c) * 12288;
        short8 pA0 = ldb(Ax, mw, 0), pA1 = ldb(Ax, mw, 1);
        short8 zA0 = ldb(Z0, mw, 0), zA1 = ldb(Z0, mw, 1);
        short8 kt0 = ldb(Pwtr, mw, 0), kt1 = ldb(Pwtr, mw, 1);
        #pragma unroll
        for (int ni = 0; ni < 2; ++ni) {
            int n = nh * 2 + ni;
            f32x4 aN = {};
            aN = __builtin_amdgcn_mfma_f32_16x16x32_bf16(zA0, ldb(Pwtr, n, 0), aN, 0, 0, 0);
            aN = __builtin_amdgcn_mfma_f32_16x16x32_bf16(zA1, ldb(Pwtr, n, 1), aN, 0, 0, 0);
            f32x4 aM = {};
            aM = __builtin_amdgcn_mfma_f32_16x16x32_bf16(kt0, ldb(Z0, 4 + n, 0), aM, 0, 0, 0);
            aM = __builtin_amdgcn_mfma_f32_16x16x32_bf16(kt1, ldb(Z0, 4 + n, 1), aM, 0, 0, 0);
            f32x4 aG;
            #pragma unroll
            for (int j = 0; j < 4; ++j) aG[j] = bf2f(Z1[(16 * mw + rb + j) * PB + 16 * n + lr]);
            aG = __builtin_amdgcn_mfma_f32_16x16x32_bf16(pA0, ldb(Z0, 4 + n, 0), aG, 0, 0, 0);
            aG = __builtin_amdgcn_mfma_f32_16x16x32_bf16(pA1, ldb(Z0, 4 + n, 1), aG, 0, 0, 0);
            f32x4 aP = {};
            aP = __builtin_amdgcn_mfma_f32_16x16x32_bf16(pA0, ldb(Z0, n, 0), aP, 0, 0, 0);
            aP = __builtin_amdgcn_mfma_f32_16x16x32_bf16(pA1, ldb(Z0, n, 1), aP, 0, 0, 0);
            #pragma unroll
            for (int j = 0; j < 4; ++j) {
                int r = 16 * mw + rb + j, cl = 16 * n + lr;
                tb[r * 64 + cl]        = f2bf(aM[j]);
                tb[4096 + r * 64 + cl] = f2bf(aG[j]);
                tb[8192 + r * 64 + cl] = f2bf(aN[j]);
                outs[((size_t)(c0 + r) * BSZ + b) * 512 + h * 64 + cl] = f2bf(aP[j]);
            }
        }
    }
}

// ---------------- phase 2a: W-only scan with register prefetch; stores bf16 W checkpoints ----------------
__global__ __launch_bounds__(256) void fwscan_w(const unsigned short* __restrict__ tiles,
                                                unsigned short* __restrict__ wchk) {
    __shared__ float Wf[64 * 68];
    const int bh = blockIdx.x;
    const int tid = threadIdx.x;
    const int w = tid >> 6, l = tid & 63;
    const int lr = l & 15, lk = (l >> 4) << 3, rb = (l >> 4) << 2;
    const int cr = l >> 3, cc8 = (l & 7) * 8;
    #pragma unroll
    for (int j = 0; j < 16; ++j) Wf[(16 * w + j) * 68 + l] = 0.f;

    const unsigned short* tb0 = tiles + (size_t)bh * 16 * 12288;
    unsigned short* wc0 = wchk + (size_t)bh * 16 * 4096;

    auto loadc = [&](short8 (&MT)[4][2], unsigned short (&NV)[4][4], int c) {
        const unsigned short* tb = tb0 + (size_t)c * 12288;
        #pragma unroll
        for (int n = 0; n < 4; ++n) {
            MT[n][0] = *(const short8*)(tb + (size_t)(16 * n + lr) * 64 + lk);
            MT[n][1] = *(const short8*)(tb + (size_t)(16 * n + lr) * 64 + 32 + lk);
            #pragma unroll
            for (int j = 0; j < 4; ++j)
                NV[n][j] = tb[8192 + (size_t)(16 * w + rb + j) * 64 + 16 * n + lr];
        }
    };
    auto stepc = [&](short8 (&MT)[4][2], unsigned short (&NV)[4][4], int c) {
        #pragma unroll
        for (int half = 0; half < 2; ++half) {
            int row = 16 * w + half * 8 + cr;
            const float* p = &Wf[row * 68 + cc8];
            f32x4 x0 = *(const f32x4*)p, x1 = *(const f32x4*)(p + 4);
            ushort8 o;
            #pragma unroll
            for (int j = 0; j < 4; ++j) { o[j] = f2bf(x0[j]); o[4 + j] = f2bf(x1[j]); }
            *(ushort8*)(wc0 + (size_t)c * 4096 + row * 64 + cc8) = o;
        }
        short8 wf0, wf1;
        {
            const float* p0 = &Wf[(16 * w + lr) * 68 + lk];
            f32x4 a0 = *(const f32x4*)p0, b0 = *(const f32x4*)(p0 + 4);
            f32x4 a1 = *(const f32x4*)(p0 + 32), b1 = *(const f32x4*)(p0 + 36);
            #pragma unroll
            for (int j = 0; j < 4; ++j) {
                wf0[j] = (short)f2bf(a0[j]); wf0[4 + j] = (short)f2bf(b0[j]);
                wf1[j] = (short)f2bf(a1[j]); wf1[4 + j] = (short)f2bf(b1[j]);
            }
        }
        #pragma unroll
        for (int n = 0; n < 4; ++n) {
            f32x4 a;
            #pragma unroll
            for (int j = 0; j < 4; ++j)
                a[j] = Wf[(16 * w + rb + j) * 68 + 16 * n + lr] + bf2f(NV[n][j]);
            a = __builtin_amdgcn_mfma_f32_16x16x32_bf16(wf0, MT[n][0], a, 0, 0, 0);
            a = __builtin_amdgcn_mfma_f32_16x16x32_bf16(wf1, MT[n][1], a, 0, 0, 0);
            #pragma unroll
            for (int j = 0; j < 4; ++j) Wf[(16 * w + rb + j) * 68 + 16 * n + lr] = a[j];
        }
    };

    short8 mtA[4][2], mtB[4][2];
    unsigned short nvA[4][4], nvB[4][4];
    loadc(mtA, nvA, 0);
    #pragma unroll 1
    for (int cc = 0; cc < 8; ++cc) {
        int c = 2 * cc;
        if (c + 1 < 16) loadc(mtB, nvB, c + 1);
        stepc(mtA, nvA, c);
        if (c + 2 < 16) loadc(mtA, nvA, c + 2);
        stepc(mtB, nvB, c + 1);
    }
}

// ---------------- phase 2b: O finalize, parallel over (chunk 1..15, bh) ----------------
__global__ __launch_bounds__(256) void fw_o(const unsigned short* __restrict__ tiles,
                                            const unsigned short* __restrict__ wchk,
                                            unsigned short* __restrict__ outs) {
    __shared__ unsigned short Ot[64 * 72];
    const int c = blockIdx.x + 1;
    const int bh = blockIdx.y;
    const int b = bh >> 3, h = bh & 7;
    const int c0 = c * 64;
    const int tid = threadIdx.x;
    const int w = tid >> 6, l = tid & 63;
    const int lr = l & 15, lk = (l >> 4) << 3, rb = (l >> 4) << 2;
    const unsigned short* G  = tiles + ((size_t)bh * 16 + c) * 12288 + 4096;
    const unsigned short* W0 = wchk + ((size_t)bh * 16 + c) * 4096;

    #pragma unroll
    for (int i = 0; i < 2; ++i) {
        int idx = i * 256 + tid;
        int t = idx >> 3, d0 = (idx & 7) * 8;
        *(ushort8*)&Ot[t * 72 + d0] =
            *(const ushort8*)(outs + ((size_t)(c0 + t) * BSZ + b) * 512 + h * 64 + d0);
    }
    __syncthreads();

    short8 g0 = *(const short8*)(G + (size_t)(16 * w + lr) * 64 + lk);
    short8 g1 = *(const short8*)(G + (size_t)(16 * w + lr) * 64 + 32 + lk);
    #pragma unroll
    for (int n = 0; n < 4; ++n) {
        short8 wf0 = *(const short8*)(W0 + (size_t)(16 * n + lr) * 64 + lk);
        short8 wf1 = *(const short8*)(W0 + (size_t)(16 * n + lr) * 64 + 32 + lk);
        f32x4 a;
        #pragma unroll
        for (int j = 0; j < 4; ++j) a[j] = bf2f(Ot[(16 * w + rb + j) * 72 + 16 * n + lr]);
        a = __builtin_amdgcn_mfma_f32_16x16x32_bf16(g0, wf0, a, 0, 0, 0);
        a = __builtin_amdgcn_mfma_f32_16x16x32_bf16(g1, wf1, a, 0, 0, 0);
        #pragma unroll
        for (int j = 0; j < 4; ++j) Ot[(16 * w + rb + j) * 72 + 16 * n + lr] = f2bf(a[j]);
    }
    __syncthreads();

    #pragma unroll
    for (int i = 0; i < 2; ++i) {
        int idx = i * 256 + tid;
        int t = idx >> 3, d0 = (idx & 7) * 8;
        *(ushort8*)(outs + ((size_t)(c0 + t) * BSZ + b) * 512 + h * 64 + d0) =
            *(const ushort8*)&Ot[t * 72 + d0];
    }
}

// ---------------- launch ----------------
extern "C" void kernel_launch(void* const* d_in, const int* in_sizes, int n_in,
                              void* d_out, int out_size, void* d_ws, size_t ws_size,
                              hipStream_t stream) {
    const float* x      = (const float*)d_in[0];
    const float* g      = (const float*)d_in[1];
    const float* be     = (const float*)d_in[2];
    const float* w_slow = (const float*)d_in[3];
    const float* w_out  = (const float*)d_in[4];
    float* out = (float*)d_out;
    char* ws = (char*)d_ws;

    unsigned short* h    = (unsigned short*)(ws);
    unsigned short* outs = (unsigned short*)(ws);                 // alias h
    unsigned short* qn   = (unsigned short*)(ws + 33554432);
    unsigned short* wchk = (unsigned short*)(ws + 33554432);      // alias qn (dead after fwtiles)
    unsigned short* kn   = (unsigned short*)(ws + 67108864);
    unsigned short* vn   = (unsigned short*)(ws + 100663296);
    float*          bet  = (float*)         (ws + 134217728);
    unsigned short* wsT  = (unsigned short*)(ws + 135266304);     // 1792*512*2
    unsigned short* woT  = (unsigned short*)(ws + 137101312);
    unsigned short* tiles= (unsigned short*)(ws + 137625600);

    if (ws_size < 238288896) return;

    ln_kernel<<<8192, 256, 0, stream>>>(x, g, be, h);
    cvt_wslow2<<<dim3(8, 25), 256, 0, stream>>>(w_slow, wsT);
    cvt_wout<<<dim3(8, 8), 256, 0, stream>>>(w_out, woT);
    gemm_qkv<<<dim3(7, MROWS / 256), 512, 0, stream>>>(h, wsT, qn, kn, vn, bet);
    fwtiles<<<BSZ * H_ * 16, 512, 0, stream>>>(qn, kn, vn, bet, tiles, outs);
    fwscan_w<<<BSZ * H_, 256, 0, stream>>>(tiles, wchk);
    fw_o<<<dim3(15, BSZ * H_), 256, 0, stream>>>(tiles, wchk, outs);
    gemm_out<<<dim3(2, MROWS / 256), 512, 0, stream>>>(outs, woT, x, out);
}

// Round 15
// 329.040 us; speedup vs baseline: 2.3705x; 2.3705x over previous
//
#include <hip/hip_runtime.h>
#include <hip/hip_bf16.h>
#include <cstdint>

using short8  = __attribute__((ext_vector_type(8))) short;
using ushort8 = __attribute__((ext_vector_type(8))) unsigned short;
using short4v = __attribute__((ext_vector_type(4))) short;
using f32x4   = __attribute__((ext_vector_type(4))) float;

#define H_    8
#define SLEN  1024
#define BSZ   32
#define INDIM 512
#define NQKV  1544   // H*(3*D+1)
#define NPAD2 1792   // 7*256 (gemm_qkv N padding)
#define MROWS 32768  // SLEN*BSZ
#define PB    72     // bf16 LDS pad stride

#define GLOAD16(gp, lp) __builtin_amdgcn_global_load_lds( \
    (const __attribute__((address_space(1))) void*)(gp),  \
    (__attribute__((address_space(3))) void*)(lp), 16, 0, 0)

#define VMCNT8() do { asm volatile("s_waitcnt vmcnt(8)" ::: "memory"); \
                      __builtin_amdgcn_sched_barrier(0); } while (0)
#define VMCNT0() do { asm volatile("s_waitcnt vmcnt(0)" ::: "memory"); \
                      __builtin_amdgcn_sched_barrier(0); } while (0)
#define SBAR()   do { __builtin_amdgcn_sched_barrier(0); \
                      __builtin_amdgcn_s_barrier(); \
                      __builtin_amdgcn_sched_barrier(0); } while (0)

static __device__ __forceinline__ float bf2f(unsigned short s) {
    return __uint_as_float(((unsigned int)s) << 16);
}
static __device__ __forceinline__ unsigned short f2bf(float f) {
    union { __hip_bfloat16 b; unsigned short u; } cv;
    cv.b = __float2bfloat16(f);    // HW RNE on gfx950
    return cv.u;
}

// ---------------- LayerNorm: x[32768][512] f32 -> h bf16 ----------------
__global__ __launch_bounds__(256) void ln_kernel(const float* __restrict__ x,
                                                 const float* __restrict__ gamma,
                                                 const float* __restrict__ betap,
                                                 unsigned short* __restrict__ h) {
    int row = blockIdx.x * 4 + (threadIdx.x >> 6);
    int l   = threadIdx.x & 63;
    const f32x4* xr = (const f32x4*)(x + (size_t)row * INDIM);
    f32x4 a = xr[l * 2], b = xr[l * 2 + 1];
    float s = 0.f, sq = 0.f;
    #pragma unroll
    for (int j = 0; j < 4; ++j) { s += a[j]; sq += a[j] * a[j]; }
    #pragma unroll
    for (int j = 0; j < 4; ++j) { s += b[j]; sq += b[j] * b[j]; }
    #pragma unroll
    for (int off = 32; off; off >>= 1) { s += __shfl_xor(s, off); sq += __shfl_xor(sq, off); }
    float mean = s * (1.f / 512.f);
    float var  = sq * (1.f / 512.f) - mean * mean;
    float rstd = rsqrtf(var + 1e-5f);
    const f32x4* g4 = (const f32x4*)gamma;
    const f32x4* b4 = (const f32x4*)betap;
    f32x4 g0 = g4[l * 2], g1 = g4[l * 2 + 1], e0 = b4[l * 2], e1 = b4[l * 2 + 1];
    short8 o;
    #pragma unroll
    for (int j = 0; j < 4; ++j) o[j]     = (short)f2bf((a[j] - mean) * rstd * g0[j] + e0[j]);
    #pragma unroll
    for (int j = 0; j < 4; ++j) o[4 + j] = (short)f2bf((b[j] - mean) * rstd * g1[j] + e1[j]);
    ((short8*)(h + (size_t)row * INDIM))[l] = o;
}

// ---------------- weight transpose+permute via LDS tiles (coalesced both sides) ----------------
__global__ __launch_bounds__(256) void cvt_wslow2(const float* __restrict__ w,
                                                  unsigned short* __restrict__ wT) {
    __shared__ float T[64][65];
    const int tid = threadIdx.x;
    const int k0 = blockIdx.x * 64;
    const int ng = blockIdx.y;                 // 0..24
    if (ng < 24) {
        const int cbase = (ng & 7) * 193 + (ng >> 3) * 64;   // q:+0 k:+64 v:+128
        const int nn = tid & 63, kk = tid >> 6;
        #pragma unroll
        for (int i = 0; i < 16; ++i)
            T[kk + 4 * i][nn] = w[(size_t)(k0 + kk + 4 * i) * NQKV + cbase + nn];
        __syncthreads();
        const int kseg = (tid & 7) * 8;
        #pragma unroll
        for (int i = 0; i < 2; ++i) {
            int nn2 = i * 32 + (tid >> 3);
            ushort8 o;
            #pragma unroll
            for (int j = 0; j < 8; ++j) o[j] = f2bf(T[kseg + j][nn2]);
            *(ushort8*)&wT[(size_t)(ng * 64 + nn2) * 512 + k0 + kseg] = o;
        }
    } else {
        for (int i = 0; i < 64; ++i) {
            int gid = i * 256 + tid;
            int nn = gid >> 6, kk = gid & 63;
            int n = 1536 + nn;
            unsigned short v = 0;
            if (n < 1544) v = f2bf(w[(size_t)(k0 + kk) * NQKV + (n - 1536) * 193 + 192]);
            wT[(size_t)n * 512 + k0 + kk] = v;
        }
    }
}
__global__ __launch_bounds__(256) void cvt_wout(const float* __restrict__ w,
                                                unsigned short* __restrict__ wT) {
    __shared__ float T[64][65];
    const int tid = threadIdx.x;
    const int k0 = blockIdx.x * 64;
    const int n0 = blockIdx.y * 64;
    const int nn = tid & 63, kk = tid >> 6;
    #pragma unroll
    for (int i = 0; i < 16; ++i)
        T[kk + 4 * i][nn] = w[(size_t)(k0 + kk + 4 * i) * 512 + n0 + nn];
    __syncthreads();
    const int kseg = (tid & 7) * 8;
    #pragma unroll
    for (int i = 0; i < 2; ++i) {
        int nn2 = i * 32 + (tid >> 3);
        ushort8 o;
        #pragma unroll
        for (int j = 0; j < 8; ++j) o[j] = f2bf(T[kseg + j][nn2]);
        *(ushort8*)&wT[(size_t)(n0 + nn2) * 512 + k0 + kseg] = o;
    }
}

// ---------------- GEMM1 fused, 256x256 tile, counted-vmcnt pipeline, LDS-staged epilogue ----------------
__global__ __launch_bounds__(512, 2) void gemm_qkv(const unsigned short* __restrict__ A,
                                                   const unsigned short* __restrict__ BT,
                                                   unsigned short* __restrict__ qn,
                                                   unsigned short* __restrict__ kn,
                                                   unsigned short* __restrict__ vn,
                                                   float* __restrict__ bet) {
    __shared__ unsigned short SMEM[65536];            // 128 KB: As/Bs dbuf, then output staging
    const int tid = threadIdx.x;
    const int id = blockIdx.y * 7 + blockIdx.x;       // 896 = 8*112
    const int newid = (id & 7) * 112 + (id >> 3);     // bijective XCD chunking
    const int bx = newid % 7;
    const int n0 = bx * 256;
    const int m0 = (newid / 7) * 256;
    const int w = tid >> 6, l = tid & 63;
    const int wm = w >> 2, wn = w & 3;
    const int lr = l & 15, lk8 = (l >> 4) * 8;
    f32x4 acc[8][4] = {};

    auto STAGE = [&](int buf, int kt) {
        #pragma unroll
        for (int c2 = 0; c2 < 4; ++c2) {
            int idx = c2 * 512 + tid;
            int row = idx >> 3, kc2 = (idx & 7) * 8;
            int lb = (c2 * 512 + (tid & 448)) * 8;
            GLOAD16(A  + (size_t)(m0 + row) * INDIM + kt + kc2, &SMEM[buf * 16384 + lb]);
            GLOAD16(BT + (size_t)(n0 + row) * INDIM + kt + kc2, &SMEM[32768 + buf * 16384 + lb]);
        }
    };
    auto COMPUTE = [&](int buf) {
        const unsigned short* As = &SMEM[buf * 16384];
        const unsigned short* Bs = &SMEM[32768 + buf * 16384];
        short8 bf2[4][2];
        #pragma unroll
        for (int ni = 0; ni < 4; ++ni)
            #pragma unroll
            for (int kk = 0; kk < 2; ++kk)
                bf2[ni][kk] = *(const short8*)&Bs[(wn * 64 + ni * 16 + lr) * 64 + kk * 32 + lk8];
        #pragma unroll
        for (int p = 0; p < 4; ++p) {
            short8 af[2][2];
            #pragma unroll
            for (int d = 0; d < 2; ++d)
                #pragma unroll
                for (int kk = 0; kk < 2; ++kk)
                    af[d][kk] = *(const short8*)&As[(wm * 128 + (2 * p + d) * 16 + lr) * 64 + kk * 32 + lk8];
            #pragma unroll
            for (int d = 0; d < 2; ++d)
                #pragma unroll
                for (int ni = 0; ni < 4; ++ni)
                    #pragma unroll
                    for (int kk = 0; kk < 2; ++kk)
                        acc[2 * p + d][ni] =
                            __builtin_amdgcn_mfma_f32_16x16x32_bf16(af[d][kk], bf2[ni][kk], acc[2 * p + d][ni], 0, 0, 0);
        }
    };

    STAGE(0, 0);
    STAGE(1, 64);
    #pragma unroll
    for (int tp = 0; tp < 4; ++tp) {
        VMCNT8();
        SBAR();
        COMPUTE(0);
        SBAR();
        if (tp < 3) {
            STAGE(0, (2 * tp + 2) * 64);
            VMCNT8();
        } else {
            VMCNT0();
        }
        SBAR();
        COMPUTE(1);
        SBAR();
        if (tp < 3) STAGE(1, (2 * tp + 3) * 64);
    }

    const int g = l >> 4, cc = l & 15;
    const int colbase = n0 + wn * 64;
    if (bx < 6) {
        const int reg = colbase >> 9;             // block-uniform (256-strip within 512-group)
        #pragma unroll
        for (int mi = 0; mi < 8; ++mi) {
            #pragma unroll
            for (int j = 0; j < 4; ++j) {
                float e0 = acc[mi][0][j], e1 = acc[mi][1][j], e2 = acc[mi][2][j], e3 = acc[mi][3][j];
                if (reg < 2) {
                    e0 = e0 > 0.f ? e0 + 1.f : __expf(e0);
                    e1 = e1 > 0.f ? e1 + 1.f : __expf(e1);
                    e2 = e2 > 0.f ? e2 + 1.f : __expf(e2);
                    e3 = e3 > 0.f ? e3 + 1.f : __expf(e3);
                    float ssum = (e0 + e1) + (e2 + e3);
                    ssum += __shfl_xor(ssum, 1);
                    ssum += __shfl_xor(ssum, 2);
                    ssum += __shfl_xor(ssum, 4);
                    ssum += __shfl_xor(ssum, 8);
                    float inv = 1.f / ssum;
                    e0 *= inv; e1 *= inv; e2 *= inv; e3 *= inv;
                }
                int lrow = wm * 128 + mi * 16 + g * 4 + j;
                int key = ((lrow >> 2) & 3) << 4;
                int cb = wn * 64;
                SMEM[lrow * 256 + ((cb +  0 + cc) ^ key)] = f2bf(e0);
                SMEM[lrow * 256 + ((cb + 16 + cc) ^ key)] = f2bf(e1);
                SMEM[lrow * 256 + ((cb + 32 + cc) ^ key)] = f2bf(e2);
                SMEM[lrow * 256 + ((cb + 48 + cc) ^ key)] = f2bf(e3);
            }
        }
        SBAR();
        unsigned short* dst = (reg == 0) ? qn : (reg == 1) ? kn : vn;
        #pragma unroll
        for (int it = 0; it < 16; ++it) {
            int idx = it * 512 + tid;
            int lrow = idx >> 5, seg = idx & 31;
            int key = ((lrow >> 2) & 3) << 4;
            ushort8 v = *(const ushort8*)&SMEM[lrow * 256 + ((seg * 8) ^ key)];
            int grow = m0 + lrow;
            int s = grow >> 5, b = grow & 31;
            int gcol = n0 + seg * 8;
            int hd = (gcol >> 6) & 7, d0 = gcol & 63;
            *(ushort8*)(dst + ((size_t)(b * H_ + hd) * SLEN + s) * 64 + d0) = v;
        }
    } else {
        if (wn == 0 && cc < 8) {
            #pragma unroll
            for (int mi = 0; mi < 8; ++mi)
                #pragma unroll
                for (int j = 0; j < 4; ++j) {
                    int row = m0 + wm * 128 + mi * 16 + g * 4 + j;
                    int s = row >> 5, b = row & 31;
                    float v = acc[mi][0][j];
                    bet[(size_t)(b * H_ + cc) * SLEN + s] = 1.f / (1.f + __expf(-v));
                }
        }
    }
}

// ---------------- GEMM2, 256x256 tile, counted-vmcnt pipeline: out = x + outs @ woT^T ----------------
__global__ __launch_bounds__(512, 2) void gemm_out(const unsigned short* __restrict__ A,
                                                   const unsigned short* __restrict__ BT,
                                                   const float* __restrict__ X,
                                                   float* __restrict__ outf) {
    __shared__ unsigned short As[2][256 * 64];
    __shared__ unsigned short Bs[2][256 * 64];
    const int tid = threadIdx.x;
    const int id = blockIdx.y * 2 + blockIdx.x;       // 256 = 8*32
    const int newid = (id & 7) * 32 + (id >> 3);
    const int n0 = (newid & 1) * 256;
    const int m0 = (newid >> 1) * 256;
    const int w = tid >> 6, l = tid & 63;
    const int wm = w >> 2, wn = w & 3;
    const int lr = l & 15, lk8 = (l >> 4) * 8;
    f32x4 acc[8][4] = {};

    auto STAGE = [&](int buf, int kt) {
        #pragma unroll
        for (int c2 = 0; c2 < 4; ++c2) {
            int idx = c2 * 512 + tid;
            int row = idx >> 3, kc2 = (idx & 7) * 8;
            int lb = (c2 * 512 + (tid & 448)) * 8;
            GLOAD16(A  + (size_t)(m0 + row) * INDIM + kt + kc2, &As[buf][lb]);
            GLOAD16(BT + (size_t)(n0 + row) * INDIM + kt + kc2, &Bs[buf][lb]);
        }
    };
    auto COMPUTE = [&](int buf) {
        short8 bf2[4][2];
        #pragma unroll
        for (int ni = 0; ni < 4; ++ni)
            #pragma unroll
            for (int kk = 0; kk < 2; ++kk)
                bf2[ni][kk] = *(const short8*)&Bs[buf][(wn * 64 + ni * 16 + lr) * 64 + kk * 32 + lk8];
        #pragma unroll
        for (int p = 0; p < 4; ++p) {
            short8 af[2][2];
            #pragma unroll
            for (int d = 0; d < 2; ++d)
                #pragma unroll
                for (int kk = 0; kk < 2; ++kk)
                    af[d][kk] = *(const short8*)&As[buf][(wm * 128 + (2 * p + d) * 16 + lr) * 64 + kk * 32 + lk8];
            #pragma unroll
            for (int d = 0; d < 2; ++d)
                #pragma unroll
                for (int ni = 0; ni < 4; ++ni)
                    #pragma unroll
                    for (int kk = 0; kk < 2; ++kk)
                        acc[2 * p + d][ni] =
                            __builtin_amdgcn_mfma_f32_16x16x32_bf16(af[d][kk], bf2[ni][kk], acc[2 * p + d][ni], 0, 0, 0);
        }
    };

    STAGE(0, 0);
    STAGE(1, 64);
    #pragma unroll
    for (int tp = 0; tp < 4; ++tp) {
        VMCNT8();
        SBAR();
        COMPUTE(0);
        SBAR();
        if (tp < 3) {
            STAGE(0, (2 * tp + 2) * 64);
            VMCNT8();
        } else {
            VMCNT0();
        }
        SBAR();
        COMPUTE(1);
        SBAR();
        if (tp < 3) STAGE(1, (2 * tp + 3) * 64);
    }

    const int g = l >> 4, cc = l & 15;
    #pragma unroll
    for (int mi = 0; mi < 8; ++mi)
        #pragma unroll
        for (int ni = 0; ni < 4; ++ni)
            #pragma unroll
            for (int j = 0; j < 4; ++j) {
                int row = m0 + wm * 128 + mi * 16 + g * 4 + j;
                int col = n0 + wn * 64 + ni * 16 + cc;
                size_t o = (size_t)row * 512 + col;
                outf[o] = X[o] + acc[mi][ni][j];
            }
}

// ---------------- phase 1 v3: per-(bh,chunk) WY tile factors, 8 waves, conflict-fixed ----------------
__global__ __launch_bounds__(512, 4) void fwtiles(const unsigned short* __restrict__ qn,
                                                  const unsigned short* __restrict__ kn,
                                                  const unsigned short* __restrict__ vn,
                                                  const float* __restrict__ beta,
                                                  unsigned short* __restrict__ tiles,
                                                  unsigned short* __restrict__ outs) {
    __shared__ unsigned short Ax[64 * PB], Atr[64 * PB], Pw[64 * PB], Pwtr[64 * PB];
    __shared__ unsigned short Z0[128 * PB], Z1[128 * PB];
    __shared__ float bv[64];
    const int bx = blockIdx.x;
    const int bh = bx >> 4, c = bx & 15;
    const int b = bh >> 3, h = bh & 7;
    const int c0 = c * 64;
    const int tid = threadIdx.x;
    const int w = tid >> 6, l = tid & 63;
    const int mw = w & 3, nh = w >> 2;
    const int lr = l & 15, lk = (l >> 4) << 3, rb = (l >> 4) << 2;
    const unsigned short* kc = kn + ((size_t)bh * SLEN + c0) * 64;
    const unsigned short* qc = qn + ((size_t)bh * SLEN + c0) * 64;
    const unsigned short* vc = vn + ((size_t)bh * SLEN + c0) * 64;
    const float* bb = beta + (size_t)bh * SLEN + c0;

    {
        #pragma unroll
        for (int i = 0; i < 2; ++i) {
            int idx = i * 512 + tid;
            int row = idx >> 3, seg = idx & 7;
            const unsigned short* src = (row < 64) ? (vc + (size_t)row * 64 + seg * 8)
                                                   : (kc + (size_t)(row - 64) * 64 + seg * 8);
            *(ushort8*)&Z1[row * PB + seg * 8] = *(const ushort8*)src;
        }
        if (tid < 64) bv[tid] = bb[tid];
        ushort8 z8 = {};
        for (int i = tid; i < 576; i += 512) { ((ushort8*)Ax)[i] = z8; ((ushort8*)Atr)[i] = z8; }
    }
    __syncthreads();

    auto ldb = [&](const unsigned short* M, int m, int kk) -> short8 {
        return *(const short8*)&M[(m * 16 + lr) * PB + kk * 32 + lk];
    };

    {
        const int zoff2 = (w >> 2) * 64;
        const int tbase = (w & 3) * 16;
        const float sgn = (w >= 4) ? -1.f : 1.f;
        ushort8 b0v, b1v;
        #pragma unroll
        for (int i = 0; i < 16; ++i) {
            int r = w * 16 + i;
            float val = sgn * bv[tbase + i] * bf2f(Z1[r * PB + l]);
            unsigned short uv = f2bf(val);
            if (i < 8) b0v[i] = uv; else b1v[i - 8] = uv;
        }
        *(ushort8*)&Z0[(zoff2 + l) * PB + tbase]     = b0v;
        *(ushort8*)&Z0[(zoff2 + l) * PB + tbase + 8] = b1v;
    }
    {
        const int pm[10] = {0, 1, 1, 2, 2, 2, 3, 3, 3, 3};
        const int pn[10] = {0, 0, 1, 0, 1, 2, 0, 1, 2, 3};
        for (int pi = w; pi < 10; pi += 8) {
            int m = pm[pi], n = pn[pi];
            short8 ka0 = *(const short8*)&Z1[(64 + 16 * m + lr) * PB + lk];
            short8 ka1 = *(const short8*)&Z1[(64 + 16 * m + lr) * PB + 32 + lk];
            short8 kb0 = *(const short8*)&Z1[(64 + 16 * n + lr) * PB + lk];
            short8 kb1 = *(const short8*)&Z1[(64 + 16 * n + lr) * PB + 32 + lk];
            f32x4 a = {};
            a = __builtin_amdgcn_mfma_f32_16x16x32_bf16(ka0, kb0, a, 0, 0, 0);
            a = __builtin_amdgcn_mfma_f32_16x16x32_bf16(ka1, kb1, a, 0, 0, 0);
            f32x4 btm = *(const f32x4*)&bv[16 * m + rb];
            short4v pk;
            #pragma unroll
            for (int j = 0; j < 4; ++j) {
                int tt = 16 * m + rb + j, s = 16 * n + lr;
                unsigned short v = (s < tt) ? f2bf(-btm[j] * a[j]) : (unsigned short)0;
                Ax[tt * PB + s] = v;
                pk[j] = (short)v;
            }
            *(short4v*)&Atr[(16 * n + lr) * PB + 16 * m + rb] = pk;
        }
    }
    __syncthreads();

    auto zprod = [&](const unsigned short* Xb, int p, const unsigned short* Zs, unsigned short* Zd) {
        const bool msk0 = (16 * mw + 15 >= p), msk1 = (16 * mw + 15 - 32 >= p);
        short8 xf0, xf1;
        if (msk0) xf0 = ldb(Xb, mw, 0);
        if (msk1) xf1 = ldb(Xb, mw, 1);
        #pragma unroll
        for (int ni = 0; ni < 4; ++ni) {
            int n = nh * 4 + ni;
            short4v zi = *(const short4v*)&Zs[(16 * n + lr) * PB + 16 * mw + rb];
            f32x4 a;
            #pragma unroll
            for (int j = 0; j < 4; ++j) a[j] = bf2f((unsigned short)zi[j]);
            if (msk0) a = __builtin_amdgcn_mfma_f32_16x16x32_bf16(xf0, ldb(Zs, n, 0), a, 0, 0, 0);
            if (msk1) a = __builtin_amdgcn_mfma_f32_16x16x32_bf16(xf1, ldb(Zs, n, 1), a, 0, 0, 0);
            short4v zo;
            #pragma unroll
            for (int j = 0; j < 4; ++j) zo[j] = (short)f2bf(a[j]);
            *(short4v*)&Zd[(16 * n + lr) * PB + 16 * mw + rb] = zo;
        }
    };
    auto powp = [&](const unsigned short* Ps, const unsigned short* Pstr, int p,
                    unsigned short* Pd, unsigned short* Pdtr, bool wrTr) {
        const bool x0 = (16 * mw + 15 >= p), x1 = (16 * mw + 15 - 32 >= p);
        short8 xf0, xf1;
        if (x0) xf0 = ldb(Ps, mw, 0);
        if (x1) xf1 = ldb(Ps, mw, 1);
        #pragma unroll
        for (int ni = 0; ni < 2; ++ni) {
            int n = nh * 2 + ni;
            const bool y0 = (31 - 16 * n >= p), y1 = (63 - 16 * n >= p);
            f32x4 a = {};
            if (x0 && y0) a = __builtin_amdgcn_mfma_f32_16x16x32_bf16(xf0, ldb(Pstr, n, 0), a, 0, 0, 0);
            if (x1 && y1) a = __builtin_amdgcn_mfma_f32_16x16x32_bf16(xf1, ldb(Pstr, n, 1), a, 0, 0, 0);
            short4v pk;
            #pragma unroll
            for (int j = 0; j < 4; ++j) {
                unsigned short v = f2bf(a[j]);
                Pd[(16 * mw + rb + j) * PB + 16 * n + lr] = v;
                pk[j] = (short)v;
            }
            if (wrTr) *(short4v*)&Pdtr[(16 * n + lr) * PB + 16 * mw + rb] = pk;
        }
    };

    zprod(Ax, 1, Z0, Z1);  powp(Ax, Atr, 1, Pw, Pwtr, true);   __syncthreads();
    zprod(Pw, 2, Z1, Z0);  powp(Pw, Pwtr, 2, Ax, Atr, true);   __syncthreads();
    zprod(Ax, 4, Z0, Z1);  powp(Ax, Atr, 4, Pw, Pwtr, true);   __syncthreads();
    zprod(Pw, 8, Z1, Z0);  powp(Pw, Pwtr, 8, Ax, Atr, true);   __syncthreads();
    zprod(Ax, 16, Z0, Z1); powp(Ax, Atr, 16, Pw, Pwtr, false); __syncthreads();
    zprod(Pw, 32, Z1, Z0);
    __syncthreads();

    {
        #pragma unroll
        for (int i = 0; i < 2; ++i) {
            int idx = i * 512 + tid;
            int row = idx >> 3, seg = idx & 7;
            const unsigned short* src = (row < 64) ? (qc + (size_t)row * 64 + seg * 8)
                                                   : (kc + (size_t)(row - 64) * 64 + seg * 8);
            *(ushort8*)&Z1[row * PB + seg * 8] = *(const ushort8*)src;
        }
    }
    __syncthreads();

    {
        short8 qa0 = *(const short8*)&Z1[(16 * mw + lr) * PB + lk];
        short8 qa1 = *(const short8*)&Z1[(16 * mw + lr) * PB + 32 + lk];
        #pragma unroll
        for (int ni = 0; ni < 2; ++ni) {
            int n = nh * 2 + ni;
            short8 kb0 = *(const short8*)&Z1[(64 + 16 * n + lr) * PB + lk];
            short8 kb1 = *(const short8*)&Z1[(64 + 16 * n + lr) * PB + 32 + lk];
            f32x4 a = {};
            a = __builtin_amdgcn_mfma_f32_16x16x32_bf16(qa0, kb0, a, 0, 0, 0);
            a = __builtin_amdgcn_mfma_f32_16x16x32_bf16(qa1, kb1, a, 0, 0, 0);
            #pragma unroll
            for (int j = 0; j < 4; ++j) {
                int tt = 16 * mw + rb + j, s = 16 * n + lr;
                Ax[tt * PB + s] = (s <= tt) ? f2bf(a[j]) : (unsigned short)0;
            }
        }
        ushort8 kv;
        #pragma unroll
        for (int j = 0; j < 8; ++j)
            kv[j] = Z1[(64 + w * 8 + j) * PB + l];
        *(ushort8*)&Pwtr[l * PB + w * 8] = kv;
    }
    __syncthreads();

    {
        unsigned short* tb = tiles + ((size_t)bh * 16 + c) * 12288;
        short8 pA0 = ldb(Ax, mw, 0), pA1 = ldb(Ax, mw, 1);
        short8 zA0 = ldb(Z0, mw, 0), zA1 = ldb(Z0, mw, 1);
        short8 kt0 = ldb(Pwtr, mw, 0), kt1 = ldb(Pwtr, mw, 1);
        #pragma unroll
        for (int ni = 0; ni < 2; ++ni) {
            int n = nh * 2 + ni;
            f32x4 aN = {};
            aN = __builtin_amdgcn_mfma_f32_16x16x32_bf16(zA0, ldb(Pwtr, n, 0), aN, 0, 0, 0);
            aN = __builtin_amdgcn_mfma_f32_16x16x32_bf16(zA1, ldb(Pwtr, n, 1), aN, 0, 0, 0);
            f32x4 aM = {};
            aM = __builtin_amdgcn_mfma_f32_16x16x32_bf16(kt0, ldb(Z0, 4 + n, 0), aM, 0, 0, 0);
            aM = __builtin_amdgcn_mfma_f32_16x16x32_bf16(kt1, ldb(Z0, 4 + n, 1), aM, 0, 0, 0);
            f32x4 aG;
            #pragma unroll
            for (int j = 0; j < 4; ++j) aG[j] = bf2f(Z1[(16 * mw + rb + j) * PB + 16 * n + lr]);
            aG = __builtin_amdgcn_mfma_f32_16x16x32_bf16(pA0, ldb(Z0, 4 + n, 0), aG, 0, 0, 0);
            aG = __builtin_amdgcn_mfma_f32_16x16x32_bf16(pA1, ldb(Z0, 4 + n, 1), aG, 0, 0, 0);
            f32x4 aP = {};
            aP = __builtin_amdgcn_mfma_f32_16x16x32_bf16(pA0, ldb(Z0, n, 0), aP, 0, 0, 0);
            aP = __builtin_amdgcn_mfma_f32_16x16x32_bf16(pA1, ldb(Z0, n, 1), aP, 0, 0, 0);
            #pragma unroll
            for (int j = 0; j < 4; ++j) {
                int r = 16 * mw + rb + j, cl = 16 * n + lr;
                tb[r * 64 + cl]        = f2bf(aM[j]);
                tb[4096 + r * 64 + cl] = f2bf(aG[j]);
                tb[8192 + r * 64 + cl] = f2bf(aN[j]);
                outs[((size_t)(c0 + r) * BSZ + b) * 512 + h * 64 + cl] = f2bf(aP[j]);
            }
        }
    }
}

// ---------------- phase 2a: W-only scan with register prefetch; stores bf16 W checkpoints ----------------
__global__ __launch_bounds__(256) void fwscan_w(const unsigned short* __restrict__ tiles,
                                                unsigned short* __restrict__ wchk) {
    __shared__ float Wf[64 * 68];
    const int bh = blockIdx.x;
    const int tid = threadIdx.x;
    const int w = tid >> 6, l = tid & 63;
    const int lr = l & 15, lk = (l >> 4) << 3, rb = (l >> 4) << 2;
    const int cr = l >> 3, cc8 = (l & 7) * 8;
    #pragma unroll
    for (int j = 0; j < 16; ++j) Wf[(16 * w + j) * 68 + l] = 0.f;

    const unsigned short* tb0 = tiles + (size_t)bh * 16 * 12288;
    unsigned short* wc0 = wchk + (size_t)bh * 16 * 4096;

    auto loadc = [&](short8 (&MT)[4][2], unsigned short (&NV)[4][4], int c) {
        const unsigned short* tb = tb0 + (size_t)c * 12288;
        #pragma unroll
        for (int n = 0; n < 4; ++n) {
            MT[n][0] = *(const short8*)(tb + (size_t)(16 * n + lr) * 64 + lk);
            MT[n][1] = *(const short8*)(tb + (size_t)(16 * n + lr) * 64 + 32 + lk);
            #pragma unroll
            for (int j = 0; j < 4; ++j)
                NV[n][j] = tb[8192 + (size_t)(16 * w + rb + j) * 64 + 16 * n + lr];
        }
    };
    auto stepc = [&](short8 (&MT)[4][2], unsigned short (&NV)[4][4], int c) {
        #pragma unroll
        for (int half = 0; half < 2; ++half) {
            int row = 16 * w + half * 8 + cr;
            const float* p = &Wf[row * 68 + cc8];
            f32x4 x0 = *(const f32x4*)p, x1 = *(const f32x4*)(p + 4);
            ushort8 o;
            #pragma unroll
            for (int j = 0; j < 4; ++j) { o[j] = f2bf(x0[j]); o[4 + j] = f2bf(x1[j]); }
            *(ushort8*)(wc0 + (size_t)c * 4096 + row * 64 + cc8) = o;
        }
        short8 wf0, wf1;
        {
            const float* p0 = &Wf[(16 * w + lr) * 68 + lk];
            f32x4 a0 = *(const f32x4*)p0, b0 = *(const f32x4*)(p0 + 4);
            f32x4 a1 = *(const f32x4*)(p0 + 32), b1 = *(const f32x4*)(p0 + 36);
            #pragma unroll
            for (int j = 0; j < 4; ++j) {
                wf0[j] = (short)f2bf(a0[j]); wf0[4 + j] = (short)f2bf(b0[j]);
                wf1[j] = (short)f2bf(a1[j]); wf1[4 + j] = (short)f2bf(b1[j]);
            }
        }
        #pragma unroll
        for (int n = 0; n < 4; ++n) {
            f32x4 a;
            #pragma unroll
            for (int j = 0; j < 4; ++j)
                a[j] = Wf[(16 * w + rb + j) * 68 + 16 * n + lr] + bf2f(NV[n][j]);
            a = __builtin_amdgcn_mfma_f32_16x16x32_bf16(wf0, MT[n][0], a, 0, 0, 0);
            a = __builtin_amdgcn_mfma_f32_16x16x32_bf16(wf1, MT[n][1], a, 0, 0, 0);
            #pragma unroll
            for (int j = 0; j < 4; ++j) Wf[(16 * w + rb + j) * 68 + 16 * n + lr] = a[j];
        }
    };

    short8 mtA[4][2], mtB[4][2];
    unsigned short nvA[4][4], nvB[4][4];
    loadc(mtA, nvA, 0);
    #pragma unroll 1
    for (int cc = 0; cc < 8; ++cc) {
        int c = 2 * cc;
        if (c + 1 < 16) loadc(mtB, nvB, c + 1);
        stepc(mtA, nvA, c);
        if (c + 2 < 16) loadc(mtA, nvA, c + 2);
        stepc(mtB, nvB, c + 1);
    }
}

// ---------------- phase 2b: O finalize, parallel over (chunk 1..15, bh) ----------------
__global__ __launch_bounds__(256) void fw_o(const unsigned short* __restrict__ tiles,
                                            const unsigned short* __restrict__ wchk,
                                            unsigned short* __restrict__ outs) {
    __shared__ unsigned short Ot[64 * 72];
    const int c = blockIdx.x + 1;
    const int bh = blockIdx.y;
    const int b = bh >> 3, h = bh & 7;
    const int c0 = c * 64;
    const int tid = threadIdx.x;
    const int w = tid >> 6, l = tid & 63;
    const int lr = l & 15, lk = (l >> 4) << 3, rb = (l >> 4) << 2;
    const unsigned short* G  = tiles + ((size_t)bh * 16 + c) * 12288 + 4096;
    const unsigned short* W0 = wchk + ((size_t)bh * 16 + c) * 4096;

    #pragma unroll
    for (int i = 0; i < 2; ++i) {
        int idx = i * 256 + tid;
        int t = idx >> 3, d0 = (idx & 7) * 8;
        *(ushort8*)&Ot[t * 72 + d0] =
            *(const ushort8*)(outs + ((size_t)(c0 + t) * BSZ + b) * 512 + h * 64 + d0);
    }
    __syncthreads();

    short8 g0 = *(const short8*)(G + (size_t)(16 * w + lr) * 64 + lk);
    short8 g1 = *(const short8*)(G + (size_t)(16 * w + lr) * 64 + 32 + lk);
    #pragma unroll
    for (int n = 0; n < 4; ++n) {
        short8 wf0 = *(const short8*)(W0 + (size_t)(16 * n + lr) * 64 + lk);
        short8 wf1 = *(const short8*)(W0 + (size_t)(16 * n + lr) * 64 + 32 + lk);
        f32x4 a;
        #pragma unroll
        for (int j = 0; j < 4; ++j) a[j] = bf2f(Ot[(16 * w + rb + j) * 72 + 16 * n + lr]);
        a = __builtin_amdgcn_mfma_f32_16x16x32_bf16(g0, wf0, a, 0, 0, 0);
        a = __builtin_amdgcn_mfma_f32_16x16x32_bf16(g1, wf1, a, 0, 0, 0);
        #pragma unroll
        for (int j = 0; j < 4; ++j) Ot[(16 * w + rb + j) * 72 + 16 * n + lr] = f2bf(a[j]);
    }
    __syncthreads();

    #pragma unroll
    for (int i = 0; i < 2; ++i) {
        int idx = i * 256 + tid;
        int t = idx >> 3, d0 = (idx & 7) * 8;
        *(ushort8*)(outs + ((size_t)(c0 + t) * BSZ + b) * 512 + h * 64 + d0) =
            *(const ushort8*)&Ot[t * 72 + d0];
    }
}

// ---------------- launch ----------------
extern "C" void kernel_launch(void* const* d_in, const int* in_sizes, int n_in,
                              void* d_out, int out_size, void* d_ws, size_t ws_size,
                              hipStream_t stream) {
    const float* x      = (const float*)d_in[0];
    const float* g      = (const float*)d_in[1];
    const float* be     = (const float*)d_in[2];
    const float* w_slow = (const float*)d_in[3];
    const float* w_out  = (const float*)d_in[4];
    float* out = (float*)d_out;
    char* ws = (char*)d_ws;

    unsigned short* h    = (unsigned short*)(ws);
    unsigned short* outs = (unsigned short*)(ws);                 // alias h
    unsigned short* qn   = (unsigned short*)(ws + 33554432);
    unsigned short* wchk = (unsigned short*)(ws + 33554432);      // alias qn (dead after fwtiles)
    unsigned short* kn   = (unsigned short*)(ws + 67108864);
    unsigned short* vn   = (unsigned short*)(ws + 100663296);
    float*          bet  = (float*)         (ws + 134217728);
    unsigned short* wsT  = (unsigned short*)(ws + 135266304);     // 1792*512*2
    unsigned short* woT  = (unsigned short*)(ws + 137101312);
    unsigned short* tiles= (unsigned short*)(ws + 137625600);

    if (ws_size < 238288896) return;

    ln_kernel<<<8192, 256, 0, stream>>>(x, g, be, h);
    cvt_wslow2<<<dim3(8, 25), 256, 0, stream>>>(w_slow, wsT);
    cvt_wout<<<dim3(8, 8), 256, 0, stream>>>(w_out, woT);
    gemm_qkv<<<dim3(7, MROWS / 256), 512, 0, stream>>>(h, wsT, qn, kn, vn, bet);
    fwtiles<<<BSZ * H_ * 16, 512, 0, stream>>>(qn, kn, vn, bet, tiles, outs);
    fwscan_w<<<BSZ * H_, 256, 0, stream>>>(tiles, wchk);
    fw_o<<<dim3(15, BSZ * H_), 256, 0, stream>>>(tiles, wchk, outs);
    gemm_out<<<dim3(2, MROWS / 256), 512, 0, stream>>>(outs, woT, x, out);
}

// Round 16
// 324.652 us; speedup vs baseline: 2.4025x; 1.0135x over previous
//
#include <hip/hip_runtime.h>
#include <hip/hip_bf16.h>
#include <cstdint>

using short8  = __attribute__((ext_vector_type(8))) short;
using ushort8 = __attribute__((ext_vector_type(8))) unsigned short;
using short4v = __attribute__((ext_vector_type(4))) short;
using f32x4   = __attribute__((ext_vector_type(4))) float;

#define H_    8
#define SLEN  1024
#define BSZ   32
#define INDIM 512
#define NQKV  1544   // H*(3*D+1)
#define NPAD2 1792   // 7*256 (gemm_qkv N padding)
#define MROWS 32768  // SLEN*BSZ
#define PB    72     // bf16 LDS pad stride

#define GLOAD16(gp, lp) __builtin_amdgcn_global_load_lds( \
    (const __attribute__((address_space(1))) void*)(gp),  \
    (__attribute__((address_space(3))) void*)(lp), 16, 0, 0)

#define VMCNT0() do { asm volatile("s_waitcnt vmcnt(0)" ::: "memory"); \
                      __builtin_amdgcn_sched_barrier(0); } while (0)
#define SBAR()   do { __builtin_amdgcn_sched_barrier(0); \
                      __builtin_amdgcn_s_barrier(); \
                      __builtin_amdgcn_sched_barrier(0); } while (0)

static __device__ __forceinline__ float bf2f(unsigned short s) {
    return __uint_as_float(((unsigned int)s) << 16);
}
static __device__ __forceinline__ unsigned short f2bf(float f) {
    union { __hip_bfloat16 b; unsigned short u; } cv;
    cv.b = __float2bfloat16(f);    // HW RNE on gfx950
    return cv.u;
}

// ---------------- LayerNorm: x[32768][512] f32 -> h bf16 ----------------
__global__ __launch_bounds__(256) void ln_kernel(const float* __restrict__ x,
                                                 const float* __restrict__ gamma,
                                                 const float* __restrict__ betap,
                                                 unsigned short* __restrict__ h) {
    int row = blockIdx.x * 4 + (threadIdx.x >> 6);
    int l   = threadIdx.x & 63;
    const f32x4* xr = (const f32x4*)(x + (size_t)row * INDIM);
    f32x4 a = xr[l * 2], b = xr[l * 2 + 1];
    float s = 0.f, sq = 0.f;
    #pragma unroll
    for (int j = 0; j < 4; ++j) { s += a[j]; sq += a[j] * a[j]; }
    #pragma unroll
    for (int j = 0; j < 4; ++j) { s += b[j]; sq += b[j] * b[j]; }
    #pragma unroll
    for (int off = 32; off; off >>= 1) { s += __shfl_xor(s, off); sq += __shfl_xor(sq, off); }
    float mean = s * (1.f / 512.f);
    float var  = sq * (1.f / 512.f) - mean * mean;
    float rstd = rsqrtf(var + 1e-5f);
    const f32x4* g4 = (const f32x4*)gamma;
    const f32x4* b4 = (const f32x4*)betap;
    f32x4 g0 = g4[l * 2], g1 = g4[l * 2 + 1], e0 = b4[l * 2], e1 = b4[l * 2 + 1];
    short8 o;
    #pragma unroll
    for (int j = 0; j < 4; ++j) o[j]     = (short)f2bf((a[j] - mean) * rstd * g0[j] + e0[j]);
    #pragma unroll
    for (int j = 0; j < 4; ++j) o[4 + j] = (short)f2bf((b[j] - mean) * rstd * g1[j] + e1[j]);
    ((short8*)(h + (size_t)row * INDIM))[l] = o;
}

// ---------------- weight transpose+permute via LDS tiles (coalesced both sides) ----------------
__global__ __launch_bounds__(256) void cvt_wslow2(const float* __restrict__ w,
                                                  unsigned short* __restrict__ wT) {
    __shared__ float T[64][65];
    const int tid = threadIdx.x;
    const int k0 = blockIdx.x * 64;
    const int ng = blockIdx.y;                 // 0..24
    if (ng < 24) {
        const int cbase = (ng & 7) * 193 + (ng >> 3) * 64;   // q:+0 k:+64 v:+128
        const int nn = tid & 63, kk = tid >> 6;
        #pragma unroll
        for (int i = 0; i < 16; ++i)
            T[kk + 4 * i][nn] = w[(size_t)(k0 + kk + 4 * i) * NQKV + cbase + nn];
        __syncthreads();
        const int kseg = (tid & 7) * 8;
        #pragma unroll
        for (int i = 0; i < 2; ++i) {
            int nn2 = i * 32 + (tid >> 3);
            ushort8 o;
            #pragma unroll
            for (int j = 0; j < 8; ++j) o[j] = f2bf(T[kseg + j][nn2]);
            *(ushort8*)&wT[(size_t)(ng * 64 + nn2) * 512 + k0 + kseg] = o;
        }
    } else {
        for (int i = 0; i < 64; ++i) {
            int gid = i * 256 + tid;
            int nn = gid >> 6, kk = gid & 63;
            int n = 1536 + nn;
            unsigned short v = 0;
            if (n < 1544) v = f2bf(w[(size_t)(k0 + kk) * NQKV + (n - 1536) * 193 + 192]);
            wT[(size_t)n * 512 + k0 + kk] = v;
        }
    }
}
__global__ __launch_bounds__(256) void cvt_wout(const float* __restrict__ w,
                                                unsigned short* __restrict__ wT) {
    __shared__ float T[64][65];
    const int tid = threadIdx.x;
    const int k0 = blockIdx.x * 64;
    const int n0 = blockIdx.y * 64;
    const int nn = tid & 63, kk = tid >> 6;
    #pragma unroll
    for (int i = 0; i < 16; ++i)
        T[kk + 4 * i][nn] = w[(size_t)(k0 + kk + 4 * i) * 512 + n0 + nn];
    __syncthreads();
    const int kseg = (tid & 7) * 8;
    #pragma unroll
    for (int i = 0; i < 2; ++i) {
        int nn2 = i * 32 + (tid >> 3);
        ushort8 o;
        #pragma unroll
        for (int j = 0; j < 8; ++j) o[j] = f2bf(T[kseg + j][nn2]);
        *(ushort8*)&wT[(size_t)(n0 + nn2) * 512 + k0 + kseg] = o;
    }
}

// ---------------- GEMM1 fused, 256x256 tile, min-2-phase (1 barrier/tile, vmcnt0 hidden) ----------------
__global__ __launch_bounds__(512, 2) void gemm_qkv(const unsigned short* __restrict__ A,
                                                   const unsigned short* __restrict__ BT,
                                                   unsigned short* __restrict__ qn,
                                                   unsigned short* __restrict__ kn,
                                                   unsigned short* __restrict__ vn,
                                                   float* __restrict__ bet) {
    __shared__ unsigned short SMEM[65536];            // 128 KB: As/Bs dbuf, then output staging
    const int tid = threadIdx.x;
    const int id = blockIdx.y * 7 + blockIdx.x;       // 896 = 8*112
    const int newid = (id & 7) * 112 + (id >> 3);     // bijective XCD chunking
    const int bx = newid % 7;
    const int n0 = bx * 256;
    const int m0 = (newid / 7) * 256;
    const int w = tid >> 6, l = tid & 63;
    const int wm = w >> 2, wn = w & 3;
    const int lr = l & 15, lk8 = (l >> 4) * 8;
    f32x4 acc[8][4] = {};

    auto STAGE = [&](int buf, int kt) {
        #pragma unroll
        for (int c2 = 0; c2 < 4; ++c2) {
            int idx = c2 * 512 + tid;
            int row = idx >> 3, kc2 = (idx & 7) * 8;
            int lb = (c2 * 512 + (tid & 448)) * 8;
            GLOAD16(A  + (size_t)(m0 + row) * INDIM + kt + kc2, &SMEM[buf * 16384 + lb]);
            GLOAD16(BT + (size_t)(n0 + row) * INDIM + kt + kc2, &SMEM[32768 + buf * 16384 + lb]);
        }
    };
    auto COMPUTE = [&](int buf) {
        const unsigned short* As = &SMEM[buf * 16384];
        const unsigned short* Bs = &SMEM[32768 + buf * 16384];
        short8 bf2[4][2];
        #pragma unroll
        for (int ni = 0; ni < 4; ++ni)
            #pragma unroll
            for (int kk = 0; kk < 2; ++kk)
                bf2[ni][kk] = *(const short8*)&Bs[(wn * 64 + ni * 16 + lr) * 64 + kk * 32 + lk8];
        #pragma unroll
        for (int p = 0; p < 4; ++p) {
            short8 af[2][2];
            #pragma unroll
            for (int d = 0; d < 2; ++d)
                #pragma unroll
                for (int kk = 0; kk < 2; ++kk)
                    af[d][kk] = *(const short8*)&As[(wm * 128 + (2 * p + d) * 16 + lr) * 64 + kk * 32 + lk8];
            #pragma unroll
            for (int d = 0; d < 2; ++d)
                #pragma unroll
                for (int ni = 0; ni < 4; ++ni)
                    #pragma unroll
                    for (int kk = 0; kk < 2; ++kk)
                        acc[2 * p + d][ni] =
                            __builtin_amdgcn_mfma_f32_16x16x32_bf16(af[d][kk], bf2[ni][kk], acc[2 * p + d][ni], 0, 0, 0);
        }
    };

    // prologue: tile 0 into buf0, drain, barrier
    STAGE(0, 0);
    VMCNT0();
    SBAR();
    // min-2-phase: stage next BEFORE compute; vmcnt(0) hidden behind MFMA; ONE barrier per tile
    #pragma unroll
    for (int t = 0; t < 8; ++t) {
        if (t < 7) STAGE((t & 1) ^ 1, (t + 1) * 64);   // into the free buffer
        COMPUTE(t & 1);                                 // current tile (landed)
        VMCNT0();                                       // next tile landed (hidden by MFMA above)
        SBAR();                                         // current buffer freed by all waves
    }

    const int g = l >> 4, cc = l & 15;
    const int colbase = n0 + wn * 64;
    if (bx < 6) {
        const int reg = colbase >> 9;             // block-uniform (256-strip within 512-group)
        #pragma unroll
        for (int mi = 0; mi < 8; ++mi) {
            #pragma unroll
            for (int j = 0; j < 4; ++j) {
                float e0 = acc[mi][0][j], e1 = acc[mi][1][j], e2 = acc[mi][2][j], e3 = acc[mi][3][j];
                if (reg < 2) {
                    e0 = e0 > 0.f ? e0 + 1.f : __expf(e0);
                    e1 = e1 > 0.f ? e1 + 1.f : __expf(e1);
                    e2 = e2 > 0.f ? e2 + 1.f : __expf(e2);
                    e3 = e3 > 0.f ? e3 + 1.f : __expf(e3);
                    float ssum = (e0 + e1) + (e2 + e3);
                    ssum += __shfl_xor(ssum, 1);
                    ssum += __shfl_xor(ssum, 2);
                    ssum += __shfl_xor(ssum, 4);
                    ssum += __shfl_xor(ssum, 8);
                    float inv = 1.f / ssum;
                    e0 *= inv; e1 *= inv; e2 *= inv; e3 *= inv;
                }
                int lrow = wm * 128 + mi * 16 + g * 4 + j;
                int key = ((lrow >> 2) & 3) << 4;
                int cb = wn * 64;
                SMEM[lrow * 256 + ((cb +  0 + cc) ^ key)] = f2bf(e0);
                SMEM[lrow * 256 + ((cb + 16 + cc) ^ key)] = f2bf(e1);
                SMEM[lrow * 256 + ((cb + 32 + cc) ^ key)] = f2bf(e2);
                SMEM[lrow * 256 + ((cb + 48 + cc) ^ key)] = f2bf(e3);
            }
        }
        SBAR();
        unsigned short* dst = (reg == 0) ? qn : (reg == 1) ? kn : vn;
        #pragma unroll
        for (int it = 0; it < 16; ++it) {
            int idx = it * 512 + tid;
            int lrow = idx >> 5, seg = idx & 31;
            int key = ((lrow >> 2) & 3) << 4;
            ushort8 v = *(const ushort8*)&SMEM[lrow * 256 + ((seg * 8) ^ key)];
            int grow = m0 + lrow;
            int s = grow >> 5, b = grow & 31;
            int gcol = n0 + seg * 8;
            int hd = (gcol >> 6) & 7, d0 = gcol & 63;
            *(ushort8*)(dst + ((size_t)(b * H_ + hd) * SLEN + s) * 64 + d0) = v;
        }
    } else {
        if (wn == 0 && cc < 8) {
            #pragma unroll
            for (int mi = 0; mi < 8; ++mi)
                #pragma unroll
                for (int j = 0; j < 4; ++j) {
                    int row = m0 + wm * 128 + mi * 16 + g * 4 + j;
                    int s = row >> 5, b = row & 31;
                    float v = acc[mi][0][j];
                    bet[(size_t)(b * H_ + cc) * SLEN + s] = 1.f / (1.f + __expf(-v));
                }
        }
    }
}

// ---------------- GEMM2, 256x256 tile, min-2-phase: out = x + outs @ woT^T ----------------
__global__ __launch_bounds__(512, 2) void gemm_out(const unsigned short* __restrict__ A,
                                                   const unsigned short* __restrict__ BT,
                                                   const float* __restrict__ X,
                                                   float* __restrict__ outf) {
    __shared__ unsigned short As[2][256 * 64];
    __shared__ unsigned short Bs[2][256 * 64];
    const int tid = threadIdx.x;
    const int id = blockIdx.y * 2 + blockIdx.x;       // 256 = 8*32
    const int newid = (id & 7) * 32 + (id >> 3);
    const int n0 = (newid & 1) * 256;
    const int m0 = (newid >> 1) * 256;
    const int w = tid >> 6, l = tid & 63;
    const int wm = w >> 2, wn = w & 3;
    const int lr = l & 15, lk8 = (l >> 4) * 8;
    f32x4 acc[8][4] = {};

    auto STAGE = [&](int buf, int kt) {
        #pragma unroll
        for (int c2 = 0; c2 < 4; ++c2) {
            int idx = c2 * 512 + tid;
            int row = idx >> 3, kc2 = (idx & 7) * 8;
            int lb = (c2 * 512 + (tid & 448)) * 8;
            GLOAD16(A  + (size_t)(m0 + row) * INDIM + kt + kc2, &As[buf][lb]);
            GLOAD16(BT + (size_t)(n0 + row) * INDIM + kt + kc2, &Bs[buf][lb]);
        }
    };
    auto COMPUTE = [&](int buf) {
        short8 bf2[4][2];
        #pragma unroll
        for (int ni = 0; ni < 4; ++ni)
            #pragma unroll
            for (int kk = 0; kk < 2; ++kk)
                bf2[ni][kk] = *(const short8*)&Bs[buf][(wn * 64 + ni * 16 + lr) * 64 + kk * 32 + lk8];
        #pragma unroll
        for (int p = 0; p < 4; ++p) {
            short8 af[2][2];
            #pragma unroll
            for (int d = 0; d < 2; ++d)
                #pragma unroll
                for (int kk = 0; kk < 2; ++kk)
                    af[d][kk] = *(const short8*)&As[buf][(wm * 128 + (2 * p + d) * 16 + lr) * 64 + kk * 32 + lk8];
            #pragma unroll
            for (int d = 0; d < 2; ++d)
                #pragma unroll
                for (int ni = 0; ni < 4; ++ni)
                    #pragma unroll
                    for (int kk = 0; kk < 2; ++kk)
                        acc[2 * p + d][ni] =
                            __builtin_amdgcn_mfma_f32_16x16x32_bf16(af[d][kk], bf2[ni][kk], acc[2 * p + d][ni], 0, 0, 0);
        }
    };

    STAGE(0, 0);
    VMCNT0();
    SBAR();
    #pragma unroll
    for (int t = 0; t < 8; ++t) {
        if (t < 7) STAGE((t & 1) ^ 1, (t + 1) * 64);
        COMPUTE(t & 1);
        VMCNT0();
        SBAR();
    }

    const int g = l >> 4, cc = l & 15;
    #pragma unroll
    for (int mi = 0; mi < 8; ++mi)
        #pragma unroll
        for (int ni = 0; ni < 4; ++ni)
            #pragma unroll
            for (int j = 0; j < 4; ++j) {
                int row = m0 + wm * 128 + mi * 16 + g * 4 + j;
                int col = n0 + wn * 64 + ni * 16 + cc;
                size_t o = (size_t)row * 512 + col;
                outf[o] = X[o] + acc[mi][ni][j];
            }
}

// ---------------- phase 1 v3: per-(bh,chunk) WY tile factors, 8 waves, conflict-fixed ----------------
__global__ __launch_bounds__(512, 4) void fwtiles(const unsigned short* __restrict__ qn,
                                                  const unsigned short* __restrict__ kn,
                                                  const unsigned short* __restrict__ vn,
                                                  const float* __restrict__ beta,
                                                  unsigned short* __restrict__ tiles,
                                                  unsigned short* __restrict__ outs) {
    __shared__ unsigned short Ax[64 * PB], Atr[64 * PB], Pw[64 * PB], Pwtr[64 * PB];
    __shared__ unsigned short Z0[128 * PB], Z1[128 * PB];
    __shared__ float bv[64];
    const int bx = blockIdx.x;
    const int bh = bx >> 4, c = bx & 15;
    const int b = bh >> 3, h = bh & 7;
    const int c0 = c * 64;
    const int tid = threadIdx.x;
    const int w = tid >> 6, l = tid & 63;
    const int mw = w & 3, nh = w >> 2;
    const int lr = l & 15, lk = (l >> 4) << 3, rb = (l >> 4) << 2;
    const unsigned short* kc = kn + ((size_t)bh * SLEN + c0) * 64;
    const unsigned short* qc = qn + ((size_t)bh * SLEN + c0) * 64;
    const unsigned short* vc = vn + ((size_t)bh * SLEN + c0) * 64;
    const float* bb = beta + (size_t)bh * SLEN + c0;

    {
        #pragma unroll
        for (int i = 0; i < 2; ++i) {
            int idx = i * 512 + tid;
            int row = idx >> 3, seg = idx & 7;
            const unsigned short* src = (row < 64) ? (vc + (size_t)row * 64 + seg * 8)
                                                   : (kc + (size_t)(row - 64) * 64 + seg * 8);
            *(ushort8*)&Z1[row * PB + seg * 8] = *(const ushort8*)src;
        }
        if (tid < 64) bv[tid] = bb[tid];
        ushort8 z8 = {};
        for (int i = tid; i < 576; i += 512) { ((ushort8*)Ax)[i] = z8; ((ushort8*)Atr)[i] = z8; }
    }
    __syncthreads();

    auto ldb = [&](const unsigned short* M, int m, int kk) -> short8 {
        return *(const short8*)&M[(m * 16 + lr) * PB + kk * 32 + lk];
    };

    {
        const int zoff2 = (w >> 2) * 64;
        const int tbase = (w & 3) * 16;
        const float sgn = (w >= 4) ? -1.f : 1.f;
        ushort8 b0v, b1v;
        #pragma unroll
        for (int i = 0; i < 16; ++i) {
            int r = w * 16 + i;
            float val = sgn * bv[tbase + i] * bf2f(Z1[r * PB + l]);
            unsigned short uv = f2bf(val);
            if (i < 8) b0v[i] = uv; else b1v[i - 8] = uv;
        }
        *(ushort8*)&Z0[(zoff2 + l) * PB + tbase]     = b0v;
        *(ushort8*)&Z0[(zoff2 + l) * PB + tbase + 8] = b1v;
    }
    {
        const int pm[10] = {0, 1, 1, 2, 2, 2, 3, 3, 3, 3};
        const int pn[10] = {0, 0, 1, 0, 1, 2, 0, 1, 2, 3};
        for (int pi = w; pi < 10; pi += 8) {
            int m = pm[pi], n = pn[pi];
            short8 ka0 = *(const short8*)&Z1[(64 + 16 * m + lr) * PB + lk];
            short8 ka1 = *(const short8*)&Z1[(64 + 16 * m + lr) * PB + 32 + lk];
            short8 kb0 = *(const short8*)&Z1[(64 + 16 * n + lr) * PB + lk];
            short8 kb1 = *(const short8*)&Z1[(64 + 16 * n + lr) * PB + 32 + lk];
            f32x4 a = {};
            a = __builtin_amdgcn_mfma_f32_16x16x32_bf16(ka0, kb0, a, 0, 0, 0);
            a = __builtin_amdgcn_mfma_f32_16x16x32_bf16(ka1, kb1, a, 0, 0, 0);
            f32x4 btm = *(const f32x4*)&bv[16 * m + rb];
            short4v pk;
            #pragma unroll
            for (int j = 0; j < 4; ++j) {
                int tt = 16 * m + rb + j, s = 16 * n + lr;
                unsigned short v = (s < tt) ? f2bf(-btm[j] * a[j]) : (unsigned short)0;
                Ax[tt * PB + s] = v;
                pk[j] = (short)v;
            }
            *(short4v*)&Atr[(16 * n + lr) * PB + 16 * m + rb] = pk;
        }
    }
    __syncthreads();

    auto zprod = [&](const unsigned short* Xb, int p, const unsigned short* Zs, unsigned short* Zd) {
        const bool msk0 = (16 * mw + 15 >= p), msk1 = (16 * mw + 15 - 32 >= p);
        short8 xf0, xf1;
        if (msk0) xf0 = ldb(Xb, mw, 0);
        if (msk1) xf1 = ldb(Xb, mw, 1);
        #pragma unroll
        for (int ni = 0; ni < 4; ++ni) {
            int n = nh * 4 + ni;
            short4v zi = *(const short4v*)&Zs[(16 * n + lr) * PB + 16 * mw + rb];
            f32x4 a;
            #pragma unroll
            for (int j = 0; j < 4; ++j) a[j] = bf2f((unsigned short)zi[j]);
            if (msk0) a = __builtin_amdgcn_mfma_f32_16x16x32_bf16(xf0, ldb(Zs, n, 0), a, 0, 0, 0);
            if (msk1) a = __builtin_amdgcn_mfma_f32_16x16x32_bf16(xf1, ldb(Zs, n, 1), a, 0, 0, 0);
            short4v zo;
            #pragma unroll
            for (int j = 0; j < 4; ++j) zo[j] = (short)f2bf(a[j]);
            *(short4v*)&Zd[(16 * n + lr) * PB + 16 * mw + rb] = zo;
        }
    };
    auto powp = [&](const unsigned short* Ps, const unsigned short* Pstr, int p,
                    unsigned short* Pd, unsigned short* Pdtr, bool wrTr) {
        const bool x0 = (16 * mw + 15 >= p), x1 = (16 * mw + 15 - 32 >= p);
        short8 xf0, xf1;
        if (x0) xf0 = ldb(Ps, mw, 0);
        if (x1) xf1 = ldb(Ps, mw, 1);
        #pragma unroll
        for (int ni = 0; ni < 2; ++ni) {
            int n = nh * 2 + ni;
            const bool y0 = (31 - 16 * n >= p), y1 = (63 - 16 * n >= p);
            f32x4 a = {};
            if (x0 && y0) a = __builtin_amdgcn_mfma_f32_16x16x32_bf16(xf0, ldb(Pstr, n, 0), a, 0, 0, 0);
            if (x1 && y1) a = __builtin_amdgcn_mfma_f32_16x16x32_bf16(xf1, ldb(Pstr, n, 1), a, 0, 0, 0);
            short4v pk;
            #pragma unroll
            for (int j = 0; j < 4; ++j) {
                unsigned short v = f2bf(a[j]);
                Pd[(16 * mw + rb + j) * PB + 16 * n + lr] = v;
                pk[j] = (short)v;
            }
            if (wrTr) *(short4v*)&Pdtr[(16 * n + lr) * PB + 16 * mw + rb] = pk;
        }
    };

    zprod(Ax, 1, Z0, Z1);  powp(Ax, Atr, 1, Pw, Pwtr, true);   __syncthreads();
    zprod(Pw, 2, Z1, Z0);  powp(Pw, Pwtr, 2, Ax, Atr, true);   __syncthreads();
    zprod(Ax, 4, Z0, Z1);  powp(Ax, Atr, 4, Pw, Pwtr, true);   __syncthreads();
    zprod(Pw, 8, Z1, Z0);  powp(Pw, Pwtr, 8, Ax, Atr, true);   __syncthreads();
    zprod(Ax, 16, Z0, Z1); powp(Ax, Atr, 16, Pw, Pwtr, false); __syncthreads();
    zprod(Pw, 32, Z1, Z0);
    __syncthreads();

    {
        #pragma unroll
        for (int i = 0; i < 2; ++i) {
            int idx = i * 512 + tid;
            int row = idx >> 3, seg = idx & 7;
            const unsigned short* src = (row < 64) ? (qc + (size_t)row * 64 + seg * 8)
                                                   : (kc + (size_t)(row - 64) * 64 + seg * 8);
            *(ushort8*)&Z1[row * PB + seg * 8] = *(const ushort8*)src;
        }
    }
    __syncthreads();

    {
        short8 qa0 = *(const short8*)&Z1[(16 * mw + lr) * PB + lk];
        short8 qa1 = *(const short8*)&Z1[(16 * mw + lr) * PB + 32 + lk];
        #pragma unroll
        for (int ni = 0; ni < 2; ++ni) {
            int n = nh * 2 + ni;
            short8 kb0 = *(const short8*)&Z1[(64 + 16 * n + lr) * PB + lk];
            short8 kb1 = *(const short8*)&Z1[(64 + 16 * n + lr) * PB + 32 + lk];
            f32x4 a = {};
            a = __builtin_amdgcn_mfma_f32_16x16x32_bf16(qa0, kb0, a, 0, 0, 0);
            a = __builtin_amdgcn_mfma_f32_16x16x32_bf16(qa1, kb1, a, 0, 0, 0);
            #pragma unroll
            for (int j = 0; j < 4; ++j) {
                int tt = 16 * mw + rb + j, s = 16 * n + lr;
                Ax[tt * PB + s] = (s <= tt) ? f2bf(a[j]) : (unsigned short)0;
            }
        }
        ushort8 kv;
        #pragma unroll
        for (int j = 0; j < 8; ++j)
            kv[j] = Z1[(64 + w * 8 + j) * PB + l];
        *(ushort8*)&Pwtr[l * PB + w * 8] = kv;
    }
    __syncthreads();

    {
        unsigned short* tb = tiles + ((size_t)bh * 16 + c) * 12288;
        short8 pA0 = ldb(Ax, mw, 0), pA1 = ldb(Ax, mw, 1);
        short8 zA0 = ldb(Z0, mw, 0), zA1 = ldb(Z0, mw, 1);
        short8 kt0 = ldb(Pwtr, mw, 0), kt1 = ldb(Pwtr, mw, 1);
        #pragma unroll
        for (int ni = 0; ni < 2; ++ni) {
            int n = nh * 2 + ni;
            f32x4 aN = {};
            aN = __builtin_amdgcn_mfma_f32_16x16x32_bf16(zA0, ldb(Pwtr, n, 0), aN, 0, 0, 0);
            aN = __builtin_amdgcn_mfma_f32_16x16x32_bf16(zA1, ldb(Pwtr, n, 1), aN, 0, 0, 0);
            f32x4 aM = {};
            aM = __builtin_amdgcn_mfma_f32_16x16x32_bf16(kt0, ldb(Z0, 4 + n, 0), aM, 0, 0, 0);
            aM = __builtin_amdgcn_mfma_f32_16x16x32_bf16(kt1, ldb(Z0, 4 + n, 1), aM, 0, 0, 0);
            f32x4 aG;
            #pragma unroll
            for (int j = 0; j < 4; ++j) aG[j] = bf2f(Z1[(16 * mw + rb + j) * PB + 16 * n + lr]);
            aG = __builtin_amdgcn_mfma_f32_16x16x32_bf16(pA0, ldb(Z0, 4 + n, 0), aG, 0, 0, 0);
            aG = __builtin_amdgcn_mfma_f32_16x16x32_bf16(pA1, ldb(Z0, 4 + n, 1), aG, 0, 0, 0);
            f32x4 aP = {};
            aP = __builtin_amdgcn_mfma_f32_16x16x32_bf16(pA0, ldb(Z0, n, 0), aP, 0, 0, 0);
            aP = __builtin_amdgcn_mfma_f32_16x16x32_bf16(pA1, ldb(Z0, n, 1), aP, 0, 0, 0);
            #pragma unroll
            for (int j = 0; j < 4; ++j) {
                int r = 16 * mw + rb + j, cl = 16 * n + lr;
                tb[r * 64 + cl]        = f2bf(aM[j]);
                tb[4096 + r * 64 + cl] = f2bf(aG[j]);
                tb[8192 + r * 64 + cl] = f2bf(aN[j]);
                outs[((size_t)(c0 + r) * BSZ + b) * 512 + h * 64 + cl] = f2bf(aP[j]);
            }
        }
    }
}

// ---------------- phase 2a: W-only scan with register prefetch; stores bf16 W checkpoints ----------------
__global__ __launch_bounds__(256) void fwscan_w(const unsigned short* __restrict__ tiles,
                                                unsigned short* __restrict__ wchk) {
    __shared__ float Wf[64 * 68];
    const int bh = blockIdx.x;
    const int tid = threadIdx.x;
    const int w = tid >> 6, l = tid & 63;
    const int lr = l & 15, lk = (l >> 4) << 3, rb = (l >> 4) << 2;
    const int cr = l >> 3, cc8 = (l & 7) * 8;
    #pragma unroll
    for (int j = 0; j < 16; ++j) Wf[(16 * w + j) * 68 + l] = 0.f;

    const unsigned short* tb0 = tiles + (size_t)bh * 16 * 12288;
    unsigned short* wc0 = wchk + (size_t)bh * 16 * 4096;

    auto loadc = [&](short8 (&MT)[4][2], unsigned short (&NV)[4][4], int c) {
        const unsigned short* tb = tb0 + (size_t)c * 12288;
        #pragma unroll
        for (int n = 0; n < 4; ++n) {
            MT[n][0] = *(const short8*)(tb + (size_t)(16 * n + lr) * 64 + lk);
            MT[n][1] = *(const short8*)(tb + (size_t)(16 * n + lr) * 64 + 32 + lk);
            #pragma unroll
            for (int j = 0; j < 4; ++j)
                NV[n][j] = tb[8192 + (size_t)(16 * w + rb + j) * 64 + 16 * n + lr];
        }
    };
    auto stepc = [&](short8 (&MT)[4][2], unsigned short (&NV)[4][4], int c) {
        #pragma unroll
        for (int half = 0; half < 2; ++half) {
            int row = 16 * w + half * 8 + cr;
            const float* p = &Wf[row * 68 + cc8];
            f32x4 x0 = *(const f32x4*)p, x1 = *(const f32x4*)(p + 4);
            ushort8 o;
            #pragma unroll
            for (int j = 0; j < 4; ++j) { o[j] = f2bf(x0[j]); o[4 + j] = f2bf(x1[j]); }
            *(ushort8*)(wc0 + (size_t)c * 4096 + row * 64 + cc8) = o;
        }
        short8 wf0, wf1;
        {
            const float* p0 = &Wf[(16 * w + lr) * 68 + lk];
            f32x4 a0 = *(const f32x4*)p0, b0 = *(const f32x4*)(p0 + 4);
            f32x4 a1 = *(const f32x4*)(p0 + 32), b1 = *(const f32x4*)(p0 + 36);
            #pragma unroll
            for (int j = 0; j < 4; ++j) {
                wf0[j] = (short)f2bf(a0[j]); wf0[4 + j] = (short)f2bf(b0[j]);
                wf1[j] = (short)f2bf(a1[j]); wf1[4 + j] = (short)f2bf(b1[j]);
            }
        }
        #pragma unroll
        for (int n = 0; n < 4; ++n) {
            f32x4 a;
            #pragma unroll
            for (int j = 0; j < 4; ++j)
                a[j] = Wf[(16 * w + rb + j) * 68 + 16 * n + lr] + bf2f(NV[n][j]);
            a = __builtin_amdgcn_mfma_f32_16x16x32_bf16(wf0, MT[n][0], a, 0, 0, 0);
            a = __builtin_amdgcn_mfma_f32_16x16x32_bf16(wf1, MT[n][1], a, 0, 0, 0);
            #pragma unroll
            for (int j = 0; j < 4; ++j) Wf[(16 * w + rb + j) * 68 + 16 * n + lr] = a[j];
        }
    };

    short8 mtA[4][2], mtB[4][2];
    unsigned short nvA[4][4], nvB[4][4];
    loadc(mtA, nvA, 0);
    #pragma unroll 1
    for (int cc = 0; cc < 8; ++cc) {
        int c = 2 * cc;
        if (c + 1 < 16) loadc(mtB, nvB, c + 1);
        stepc(mtA, nvA, c);
        if (c + 2 < 16) loadc(mtA, nvA, c + 2);
        stepc(mtB, nvB, c + 1);
    }
}

// ---------------- phase 2b: O finalize, parallel over (chunk 1..15, bh) ----------------
__global__ __launch_bounds__(256) void fw_o(const unsigned short* __restrict__ tiles,
                                            const unsigned short* __restrict__ wchk,
                                            unsigned short* __restrict__ outs) {
    __shared__ unsigned short Ot[64 * 72];
    const int c = blockIdx.x + 1;
    const int bh = blockIdx.y;
    const int b = bh >> 3, h = bh & 7;
    const int c0 = c * 64;
    const int tid = threadIdx.x;
    const int w = tid >> 6, l = tid & 63;
    const int lr = l & 15, lk = (l >> 4) << 3, rb = (l >> 4) << 2;
    const unsigned short* G  = tiles + ((size_t)bh * 16 + c) * 12288 + 4096;
    const unsigned short* W0 = wchk + ((size_t)bh * 16 + c) * 4096;

    #pragma unroll
    for (int i = 0; i < 2; ++i) {
        int idx = i * 256 + tid;
        int t = idx >> 3, d0 = (idx & 7) * 8;
        *(ushort8*)&Ot[t * 72 + d0] =
            *(const ushort8*)(outs + ((size_t)(c0 + t) * BSZ + b) * 512 + h * 64 + d0);
    }
    __syncthreads();

    short8 g0 = *(const short8*)(G + (size_t)(16 * w + lr) * 64 + lk);
    short8 g1 = *(const short8*)(G + (size_t)(16 * w + lr) * 64 + 32 + lk);
    #pragma unroll
    for (int n = 0; n < 4; ++n) {
        short8 wf0 = *(const short8*)(W0 + (size_t)(16 * n + lr) * 64 + lk);
        short8 wf1 = *(const short8*)(W0 + (size_t)(16 * n + lr) * 64 + 32 + lk);
        f32x4 a;
        #pragma unroll
        for (int j = 0; j < 4; ++j) a[j] = bf2f(Ot[(16 * w + rb + j) * 72 + 16 * n + lr]);
        a = __builtin_amdgcn_mfma_f32_16x16x32_bf16(g0, wf0, a, 0, 0, 0);
        a = __builtin_amdgcn_mfma_f32_16x16x32_bf16(g1, wf1, a, 0, 0, 0);
        #pragma unroll
        for (int j = 0; j < 4; ++j) Ot[(16 * w + rb + j) * 72 + 16 * n + lr] = f2bf(a[j]);
    }
    __syncthreads();

    #pragma unroll
    for (int i = 0; i < 2; ++i) {
        int idx = i * 256 + tid;
        int t = idx >> 3, d0 = (idx & 7) * 8;
        *(ushort8*)(outs + ((size_t)(c0 + t) * BSZ + b) * 512 + h * 64 + d0) =
            *(const ushort8*)&Ot[t * 72 + d0];
    }
}

// ---------------- launch ----------------
extern "C" void kernel_launch(void* const* d_in, const int* in_sizes, int n_in,
                              void* d_out, int out_size, void* d_ws, size_t ws_size,
                              hipStream_t stream) {
    const float* x      = (const float*)d_in[0];
    const float* g      = (const float*)d_in[1];
    const float* be     = (const float*)d_in[2];
    const float* w_slow = (const float*)d_in[3];
    const float* w_out  = (const float*)d_in[4];
    float* out = (float*)d_out;
    char* ws = (char*)d_ws;

    unsigned short* h    = (unsigned short*)(ws);
    unsigned short* outs = (unsigned short*)(ws);                 // alias h
    unsigned short* qn   = (unsigned short*)(ws + 33554432);
    unsigned short* wchk = (unsigned short*)(ws + 33554432);      // alias qn (dead after fwtiles)
    unsigned short* kn   = (unsigned short*)(ws + 67108864);
    unsigned short* vn   = (unsigned short*)(ws + 100663296);
    float*          bet  = (float*)         (ws + 134217728);
    unsigned short* wsT  = (unsigned short*)(ws + 135266304);     // 1792*512*2
    unsigned short* woT  = (unsigned short*)(ws + 137101312);
    unsigned short* tiles= (unsigned short*)(ws + 137625600);

    if (ws_size < 238288896) return;

    ln_kernel<<<8192, 256, 0, stream>>>(x, g, be, h);
    cvt_wslow2<<<dim3(8, 25), 256, 0, stream>>>(w_slow, wsT);
    cvt_wout<<<dim3(8, 8), 256, 0, stream>>>(w_out, woT);
    gemm_qkv<<<dim3(7, MROWS / 256), 512, 0, stream>>>(h, wsT, qn, kn, vn, bet);
    fwtiles<<<BSZ * H_ * 16, 512, 0, stream>>>(qn, kn, vn, bet, tiles, outs);
    fwscan_w<<<BSZ * H_, 256, 0, stream>>>(tiles, wchk);
    fw_o<<<dim3(15, BSZ * H_), 256, 0, stream>>>(tiles, wchk, outs);
    gemm_out<<<dim3(2, MROWS / 256), 512, 0, stream>>>(outs, woT, x, out);
}

// Round 17
// 308.127 us; speedup vs baseline: 2.5314x; 1.0536x over previous
//
#include <hip/hip_runtime.h>
#include <hip/hip_bf16.h>
#include <cstdint>

using short8  = __attribute__((ext_vector_type(8))) short;
using ushort8 = __attribute__((ext_vector_type(8))) unsigned short;
using short4v = __attribute__((ext_vector_type(4))) short;
using f32x4   = __attribute__((ext_vector_type(4))) float;

#define H_    8
#define SLEN  1024
#define BSZ   32
#define INDIM 512
#define NQKV  1544   // H*(3*D+1)
#define NPAD2 1792   // 7*256 (gemm_qkv N padding)
#define MROWS 32768  // SLEN*BSZ
#define PB    72     // bf16 LDS pad stride

#define GLOAD16(gp, lp) __builtin_amdgcn_global_load_lds( \
    (const __attribute__((address_space(1))) void*)(gp),  \
    (__attribute__((address_space(3))) void*)(lp), 16, 0, 0)

#define VMCNT0() do { asm volatile("s_waitcnt vmcnt(0)" ::: "memory"); \
                      __builtin_amdgcn_sched_barrier(0); } while (0)
#define SBAR()   do { __builtin_amdgcn_sched_barrier(0); \
                      __builtin_amdgcn_s_barrier(); \
                      __builtin_amdgcn_sched_barrier(0); } while (0)

static __device__ __forceinline__ float bf2f(unsigned short s) {
    return __uint_as_float(((unsigned int)s) << 16);
}
static __device__ __forceinline__ unsigned short f2bf(float f) {
    union { __hip_bfloat16 b; unsigned short u; } cv;
    cv.b = __float2bfloat16(f);    // HW RNE on gfx950
    return cv.u;
}

// ---------------- LayerNorm: x[32768][512] f32 -> h bf16 ----------------
__global__ __launch_bounds__(256) void ln_kernel(const float* __restrict__ x,
                                                 const float* __restrict__ gamma,
                                                 const float* __restrict__ betap,
                                                 unsigned short* __restrict__ h) {
    int row = blockIdx.x * 4 + (threadIdx.x >> 6);
    int l   = threadIdx.x & 63;
    const f32x4* xr = (const f32x4*)(x + (size_t)row * INDIM);
    f32x4 a = xr[l * 2], b = xr[l * 2 + 1];
    float s = 0.f, sq = 0.f;
    #pragma unroll
    for (int j = 0; j < 4; ++j) { s += a[j]; sq += a[j] * a[j]; }
    #pragma unroll
    for (int j = 0; j < 4; ++j) { s += b[j]; sq += b[j] * b[j]; }
    #pragma unroll
    for (int off = 32; off; off >>= 1) { s += __shfl_xor(s, off); sq += __shfl_xor(sq, off); }
    float mean = s * (1.f / 512.f);
    float var  = sq * (1.f / 512.f) - mean * mean;
    float rstd = rsqrtf(var + 1e-5f);
    const f32x4* g4 = (const f32x4*)gamma;
    const f32x4* b4 = (const f32x4*)betap;
    f32x4 g0 = g4[l * 2], g1 = g4[l * 2 + 1], e0 = b4[l * 2], e1 = b4[l * 2 + 1];
    short8 o;
    #pragma unroll
    for (int j = 0; j < 4; ++j) o[j]     = (short)f2bf((a[j] - mean) * rstd * g0[j] + e0[j]);
    #pragma unroll
    for (int j = 0; j < 4; ++j) o[4 + j] = (short)f2bf((b[j] - mean) * rstd * g1[j] + e1[j]);
    ((short8*)(h + (size_t)row * INDIM))[l] = o;
}

// ---------------- weight transpose+permute via LDS tiles (coalesced both sides) ----------------
__global__ __launch_bounds__(256) void cvt_wslow2(const float* __restrict__ w,
                                                  unsigned short* __restrict__ wT) {
    __shared__ float T[64][65];
    const int tid = threadIdx.x;
    const int k0 = blockIdx.x * 64;
    const int ng = blockIdx.y;                 // 0..24
    if (ng < 24) {
        const int cbase = (ng & 7) * 193 + (ng >> 3) * 64;   // q:+0 k:+64 v:+128
        const int nn = tid & 63, kk = tid >> 6;
        #pragma unroll
        for (int i = 0; i < 16; ++i)
            T[kk + 4 * i][nn] = w[(size_t)(k0 + kk + 4 * i) * NQKV + cbase + nn];
        __syncthreads();
        const int kseg = (tid & 7) * 8;
        #pragma unroll
        for (int i = 0; i < 2; ++i) {
            int nn2 = i * 32 + (tid >> 3);
            ushort8 o;
            #pragma unroll
            for (int j = 0; j < 8; ++j) o[j] = f2bf(T[kseg + j][nn2]);
            *(ushort8*)&wT[(size_t)(ng * 64 + nn2) * 512 + k0 + kseg] = o;
        }
    } else {
        for (int i = 0; i < 64; ++i) {
            int gid = i * 256 + tid;
            int nn = gid >> 6, kk = gid & 63;
            int n = 1536 + nn;
            unsigned short v = 0;
            if (n < 1544) v = f2bf(w[(size_t)(k0 + kk) * NQKV + (n - 1536) * 193 + 192]);
            wT[(size_t)n * 512 + k0 + kk] = v;
        }
    }
}
__global__ __launch_bounds__(256) void cvt_wout(const float* __restrict__ w,
                                                unsigned short* __restrict__ wT) {
    __shared__ float T[64][65];
    const int tid = threadIdx.x;
    const int k0 = blockIdx.x * 64;
    const int n0 = blockIdx.y * 64;
    const int nn = tid & 63, kk = tid >> 6;
    #pragma unroll
    for (int i = 0; i < 16; ++i)
        T[kk + 4 * i][nn] = w[(size_t)(k0 + kk + 4 * i) * 512 + n0 + nn];
    __syncthreads();
    const int kseg = (tid & 7) * 8;
    #pragma unroll
    for (int i = 0; i < 2; ++i) {
        int nn2 = i * 32 + (tid >> 3);
        ushort8 o;
        #pragma unroll
        for (int j = 0; j < 8; ++j) o[j] = f2bf(T[kseg + j][nn2]);
        *(ushort8*)&wT[(size_t)(n0 + nn2) * 512 + k0 + kseg] = o;
    }
}

// ---------------- GEMM1 fused, 256x256 tile, min-2-phase + T2 source-swizzle ----------------
__global__ __launch_bounds__(512, 2) void gemm_qkv(const unsigned short* __restrict__ A,
                                                   const unsigned short* __restrict__ BT,
                                                   unsigned short* __restrict__ qn,
                                                   unsigned short* __restrict__ kn,
                                                   unsigned short* __restrict__ vn,
                                                   float* __restrict__ bet) {
    __shared__ unsigned short SMEM[65536];            // 128 KB: As/Bs dbuf, then output staging
    const int tid = threadIdx.x;
    const int id = blockIdx.y * 7 + blockIdx.x;       // 896 = 8*112
    const int newid = (id & 7) * 112 + (id >> 3);     // bijective XCD chunking
    const int bx = newid % 7;
    const int n0 = bx * 256;
    const int m0 = (newid / 7) * 256;
    const int w = tid >> 6, l = tid & 63;
    const int wm = w >> 2, wn = w & 3;
    const int lr = l & 15;
    const int sB = l >> 4;                            // col-slot base within kk group
    const int xk = lr & 7;                            // per-lane XOR key (row&7 of frag rows)
    f32x4 acc[8][4] = {};

    // T2 rule#21: linear LDS dest + XOR-permuted GLOBAL source (slot idx&7 ^ row&7)
    auto STAGE = [&](int buf, int kt) {
        #pragma unroll
        for (int c2 = 0; c2 < 4; ++c2) {
            int idx = c2 * 512 + tid;
            int row = idx >> 3, kc2 = ((idx ^ (idx >> 3)) & 7) * 8;
            int lb = (c2 * 512 + (tid & 448)) * 8;
            GLOAD16(A  + (size_t)(m0 + row) * INDIM + kt + kc2, &SMEM[buf * 16384 + lb]);
            GLOAD16(BT + (size_t)(n0 + row) * INDIM + kt + kc2, &SMEM[32768 + buf * 16384 + lb]);
        }
    };
    auto COMPUTE = [&](int buf) {
        const unsigned short* As = &SMEM[buf * 16384];
        const unsigned short* Bs = &SMEM[32768 + buf * 16384];
        short8 bf2[4][2];
        #pragma unroll
        for (int ni = 0; ni < 4; ++ni)
            #pragma unroll
            for (int kk = 0; kk < 2; ++kk)
                bf2[ni][kk] = *(const short8*)&Bs[(wn * 64 + ni * 16 + lr) * 64 +
                                                  (((kk * 4 + sB) ^ xk) * 8)];
        #pragma unroll
        for (int p = 0; p < 4; ++p) {
            short8 af[2][2];
            #pragma unroll
            for (int d = 0; d < 2; ++d)
                #pragma unroll
                for (int kk = 0; kk < 2; ++kk)
                    af[d][kk] = *(const short8*)&As[(wm * 128 + (2 * p + d) * 16 + lr) * 64 +
                                                    (((kk * 4 + sB) ^ xk) * 8)];
            #pragma unroll
            for (int d = 0; d < 2; ++d)
                #pragma unroll
                for (int ni = 0; ni < 4; ++ni)
                    #pragma unroll
                    for (int kk = 0; kk < 2; ++kk)
                        acc[2 * p + d][ni] =
                            __builtin_amdgcn_mfma_f32_16x16x32_bf16(af[d][kk], bf2[ni][kk], acc[2 * p + d][ni], 0, 0, 0);
        }
    };

    STAGE(0, 0);
    VMCNT0();
    SBAR();
    #pragma unroll
    for (int t = 0; t < 8; ++t) {
        if (t < 7) STAGE((t & 1) ^ 1, (t + 1) * 64);   // into the free buffer
        COMPUTE(t & 1);                                 // current tile (landed)
        VMCNT0();                                       // next tile landed (hidden by MFMA above)
        SBAR();                                         // current buffer freed by all waves
    }

    const int g = l >> 4, cc = l & 15;
    const int colbase = n0 + wn * 64;
    if (bx < 6) {
        const int reg = colbase >> 9;             // block-uniform (256-strip within 512-group)
        #pragma unroll
        for (int mi = 0; mi < 8; ++mi) {
            #pragma unroll
            for (int j = 0; j < 4; ++j) {
                float e0 = acc[mi][0][j], e1 = acc[mi][1][j], e2 = acc[mi][2][j], e3 = acc[mi][3][j];
                if (reg < 2) {
                    e0 = e0 > 0.f ? e0 + 1.f : __expf(e0);
                    e1 = e1 > 0.f ? e1 + 1.f : __expf(e1);
                    e2 = e2 > 0.f ? e2 + 1.f : __expf(e2);
                    e3 = e3 > 0.f ? e3 + 1.f : __expf(e3);
                    float ssum = (e0 + e1) + (e2 + e3);
                    ssum += __shfl_xor(ssum, 1);
                    ssum += __shfl_xor(ssum, 2);
                    ssum += __shfl_xor(ssum, 4);
                    ssum += __shfl_xor(ssum, 8);
                    float inv = 1.f / ssum;
                    e0 *= inv; e1 *= inv; e2 *= inv; e3 *= inv;
                }
                int lrow = wm * 128 + mi * 16 + g * 4 + j;
                int key = ((lrow >> 2) & 3) << 4;
                int cb = wn * 64;
                SMEM[lrow * 256 + ((cb +  0 + cc) ^ key)] = f2bf(e0);
                SMEM[lrow * 256 + ((cb + 16 + cc) ^ key)] = f2bf(e1);
                SMEM[lrow * 256 + ((cb + 32 + cc) ^ key)] = f2bf(e2);
                SMEM[lrow * 256 + ((cb + 48 + cc) ^ key)] = f2bf(e3);
            }
        }
        SBAR();
        unsigned short* dst = (reg == 0) ? qn : (reg == 1) ? kn : vn;
        #pragma unroll
        for (int it = 0; it < 16; ++it) {
            int idx = it * 512 + tid;
            int lrow = idx >> 5, seg = idx & 31;
            int key = ((lrow >> 2) & 3) << 4;
            ushort8 v = *(const ushort8*)&SMEM[lrow * 256 + ((seg * 8) ^ key)];
            int grow = m0 + lrow;
            int s = grow >> 5, b = grow & 31;
            int gcol = n0 + seg * 8;
            int hd = (gcol >> 6) & 7, d0 = gcol & 63;
            *(ushort8*)(dst + ((size_t)(b * H_ + hd) * SLEN + s) * 64 + d0) = v;
        }
    } else {
        if (wn == 0 && cc < 8) {
            #pragma unroll
            for (int mi = 0; mi < 8; ++mi)
                #pragma unroll
                for (int j = 0; j < 4; ++j) {
                    int row = m0 + wm * 128 + mi * 16 + g * 4 + j;
                    int s = row >> 5, b = row & 31;
                    float v = acc[mi][0][j];
                    bet[(size_t)(b * H_ + cc) * SLEN + s] = 1.f / (1.f + __expf(-v));
                }
        }
    }
}

// ---------------- GEMM2, 256x256 tile, min-2-phase + T2 source-swizzle ----------------
__global__ __launch_bounds__(512, 2) void gemm_out(const unsigned short* __restrict__ A,
                                                   const unsigned short* __restrict__ BT,
                                                   const float* __restrict__ X,
                                                   float* __restrict__ outf) {
    __shared__ unsigned short As[2][256 * 64];
    __shared__ unsigned short Bs[2][256 * 64];
    const int tid = threadIdx.x;
    const int id = blockIdx.y * 2 + blockIdx.x;       // 256 = 8*32
    const int newid = (id & 7) * 32 + (id >> 3);
    const int n0 = (newid & 1) * 256;
    const int m0 = (newid >> 1) * 256;
    const int w = tid >> 6, l = tid & 63;
    const int wm = w >> 2, wn = w & 3;
    const int lr = l & 15;
    const int sB = l >> 4;
    const int xk = lr & 7;
    f32x4 acc[8][4] = {};

    auto STAGE = [&](int buf, int kt) {
        #pragma unroll
        for (int c2 = 0; c2 < 4; ++c2) {
            int idx = c2 * 512 + tid;
            int row = idx >> 3, kc2 = ((idx ^ (idx >> 3)) & 7) * 8;
            int lb = (c2 * 512 + (tid & 448)) * 8;
            GLOAD16(A  + (size_t)(m0 + row) * INDIM + kt + kc2, &As[buf][lb]);
            GLOAD16(BT + (size_t)(n0 + row) * INDIM + kt + kc2, &Bs[buf][lb]);
        }
    };
    auto COMPUTE = [&](int buf) {
        short8 bf2[4][2];
        #pragma unroll
        for (int ni = 0; ni < 4; ++ni)
            #pragma unroll
            for (int kk = 0; kk < 2; ++kk)
                bf2[ni][kk] = *(const short8*)&Bs[buf][(wn * 64 + ni * 16 + lr) * 64 +
                                                       (((kk * 4 + sB) ^ xk) * 8)];
        #pragma unroll
        for (int p = 0; p < 4; ++p) {
            short8 af[2][2];
            #pragma unroll
            for (int d = 0; d < 2; ++d)
                #pragma unroll
                for (int kk = 0; kk < 2; ++kk)
                    af[d][kk] = *(const short8*)&As[buf][(wm * 128 + (2 * p + d) * 16 + lr) * 64 +
                                                         (((kk * 4 + sB) ^ xk) * 8)];
            #pragma unroll
            for (int d = 0; d < 2; ++d)
                #pragma unroll
                for (int ni = 0; ni < 4; ++ni)
                    #pragma unroll
                    for (int kk = 0; kk < 2; ++kk)
                        acc[2 * p + d][ni] =
                            __builtin_amdgcn_mfma_f32_16x16x32_bf16(af[d][kk], bf2[ni][kk], acc[2 * p + d][ni], 0, 0, 0);
        }
    };

    STAGE(0, 0);
    VMCNT0();
    SBAR();
    #pragma unroll
    for (int t = 0; t < 8; ++t) {
        if (t < 7) STAGE((t & 1) ^ 1, (t + 1) * 64);
        COMPUTE(t & 1);
        VMCNT0();
        SBAR();
    }

    const int g = l >> 4, cc = l & 15;
    #pragma unroll
    for (int mi = 0; mi < 8; ++mi)
        #pragma unroll
        for (int ni = 0; ni < 4; ++ni)
            #pragma unroll
            for (int j = 0; j < 4; ++j) {
                int row = m0 + wm * 128 + mi * 16 + g * 4 + j;
                int col = n0 + wn * 64 + ni * 16 + cc;
                size_t o = (size_t)row * 512 + col;
                outf[o] = X[o] + acc[mi][ni][j];
            }
}

// ---------------- phase 1 v3: per-(bh,chunk) WY tile factors, 8 waves, conflict-fixed ----------------
__global__ __launch_bounds__(512, 4) void fwtiles(const unsigned short* __restrict__ qn,
                                                  const unsigned short* __restrict__ kn,
                                                  const unsigned short* __restrict__ vn,
                                                  const float* __restrict__ beta,
                                                  unsigned short* __restrict__ tiles,
                                                  unsigned short* __restrict__ outs) {
    __shared__ unsigned short Ax[64 * PB], Atr[64 * PB], Pw[64 * PB], Pwtr[64 * PB];
    __shared__ unsigned short Z0[128 * PB], Z1[128 * PB];
    __shared__ float bv[64];
    const int bx = blockIdx.x;
    const int bh = bx >> 4, c = bx & 15;
    const int b = bh >> 3, h = bh & 7;
    const int c0 = c * 64;
    const int tid = threadIdx.x;
    const int w = tid >> 6, l = tid & 63;
    const int mw = w & 3, nh = w >> 2;
    const int lr = l & 15, lk = (l >> 4) << 3, rb = (l >> 4) << 2;
    const unsigned short* kc = kn + ((size_t)bh * SLEN + c0) * 64;
    const unsigned short* qc = qn + ((size_t)bh * SLEN + c0) * 64;
    const unsigned short* vc = vn + ((size_t)bh * SLEN + c0) * 64;
    const float* bb = beta + (size_t)bh * SLEN + c0;

    {
        #pragma unroll
        for (int i = 0; i < 2; ++i) {
            int idx = i * 512 + tid;
            int row = idx >> 3, seg = idx & 7;
            const unsigned short* src = (row < 64) ? (vc + (size_t)row * 64 + seg * 8)
                                                   : (kc + (size_t)(row - 64) * 64 + seg * 8);
            *(ushort8*)&Z1[row * PB + seg * 8] = *(const ushort8*)src;
        }
        if (tid < 64) bv[tid] = bb[tid];
        ushort8 z8 = {};
        for (int i = tid; i < 576; i += 512) { ((ushort8*)Ax)[i] = z8; ((ushort8*)Atr)[i] = z8; }
    }
    __syncthreads();

    auto ldb = [&](const unsigned short* M, int m, int kk) -> short8 {
        return *(const short8*)&M[(m * 16 + lr) * PB + kk * 32 + lk];
    };

    {
        const int zoff2 = (w >> 2) * 64;
        const int tbase = (w & 3) * 16;
        const float sgn = (w >= 4) ? -1.f : 1.f;
        ushort8 b0v, b1v;
        #pragma unroll
        for (int i = 0; i < 16; ++i) {
            int r = w * 16 + i;
            float val = sgn * bv[tbase + i] * bf2f(Z1[r * PB + l]);
            unsigned short uv = f2bf(val);
            if (i < 8) b0v[i] = uv; else b1v[i - 8] = uv;
        }
        *(ushort8*)&Z0[(zoff2 + l) * PB + tbase]     = b0v;
        *(ushort8*)&Z0[(zoff2 + l) * PB + tbase + 8] = b1v;
    }
    {
        const int pm[10] = {0, 1, 1, 2, 2, 2, 3, 3, 3, 3};
        const int pn[10] = {0, 0, 1, 0, 1, 2, 0, 1, 2, 3};
        for (int pi = w; pi < 10; pi += 8) {
            int m = pm[pi], n = pn[pi];
            short8 ka0 = *(const short8*)&Z1[(64 + 16 * m + lr) * PB + lk];
            short8 ka1 = *(const short8*)&Z1[(64 + 16 * m + lr) * PB + 32 + lk];
            short8 kb0 = *(const short8*)&Z1[(64 + 16 * n + lr) * PB + lk];
            short8 kb1 = *(const short8*)&Z1[(64 + 16 * n + lr) * PB + 32 + lk];
            f32x4 a = {};
            a = __builtin_amdgcn_mfma_f32_16x16x32_bf16(ka0, kb0, a, 0, 0, 0);
            a = __builtin_amdgcn_mfma_f32_16x16x32_bf16(ka1, kb1, a, 0, 0, 0);
            f32x4 btm = *(const f32x4*)&bv[16 * m + rb];
            short4v pk;
            #pragma unroll
            for (int j = 0; j < 4; ++j) {
                int tt = 16 * m + rb + j, s = 16 * n + lr;
                unsigned short v = (s < tt) ? f2bf(-btm[j] * a[j]) : (unsigned short)0;
                Ax[tt * PB + s] = v;
                pk[j] = (short)v;
            }
            *(short4v*)&Atr[(16 * n + lr) * PB + 16 * m + rb] = pk;
        }
    }
    __syncthreads();

    auto zprod = [&](const unsigned short* Xb, int p, const unsigned short* Zs, unsigned short* Zd) {
        const bool msk0 = (16 * mw + 15 >= p), msk1 = (16 * mw + 15 - 32 >= p);
        short8 xf0, xf1;
        if (msk0) xf0 = ldb(Xb, mw, 0);
        if (msk1) xf1 = ldb(Xb, mw, 1);
        #pragma unroll
        for (int ni = 0; ni < 4; ++ni) {
            int n = nh * 4 + ni;
            short4v zi = *(const short4v*)&Zs[(16 * n + lr) * PB + 16 * mw + rb];
            f32x4 a;
            #pragma unroll
            for (int j = 0; j < 4; ++j) a[j] = bf2f((unsigned short)zi[j]);
            if (msk0) a = __builtin_amdgcn_mfma_f32_16x16x32_bf16(xf0, ldb(Zs, n, 0), a, 0, 0, 0);
            if (msk1) a = __builtin_amdgcn_mfma_f32_16x16x32_bf16(xf1, ldb(Zs, n, 1), a, 0, 0, 0);
            short4v zo;
            #pragma unroll
            for (int j = 0; j < 4; ++j) zo[j] = (short)f2bf(a[j]);
            *(short4v*)&Zd[(16 * n + lr) * PB + 16 * mw + rb] = zo;
        }
    };
    auto powp = [&](const unsigned short* Ps, const unsigned short* Pstr, int p,
                    unsigned short* Pd, unsigned short* Pdtr, bool wrTr) {
        const bool x0 = (16 * mw + 15 >= p), x1 = (16 * mw + 15 - 32 >= p);
        short8 xf0, xf1;
        if (x0) xf0 = ldb(Ps, mw, 0);
        if (x1) xf1 = ldb(Ps, mw, 1);
        #pragma unroll
        for (int ni = 0; ni < 2; ++ni) {
            int n = nh * 2 + ni;
            const bool y0 = (31 - 16 * n >= p), y1 = (63 - 16 * n >= p);
            f32x4 a = {};
            if (x0 && y0) a = __builtin_amdgcn_mfma_f32_16x16x32_bf16(xf0, ldb(Pstr, n, 0), a, 0, 0, 0);
            if (x1 && y1) a = __builtin_amdgcn_mfma_f32_16x16x32_bf16(xf1, ldb(Pstr, n, 1), a, 0, 0, 0);
            short4v pk;
            #pragma unroll
            for (int j = 0; j < 4; ++j) {
                unsigned short v = f2bf(a[j]);
                Pd[(16 * mw + rb + j) * PB + 16 * n + lr] = v;
                pk[j] = (short)v;
            }
            if (wrTr) *(short4v*)&Pdtr[(16 * n + lr) * PB + 16 * mw + rb] = pk;
        }
    };

    zprod(Ax, 1, Z0, Z1);  powp(Ax, Atr, 1, Pw, Pwtr, true);   __syncthreads();
    zprod(Pw, 2, Z1, Z0);  powp(Pw, Pwtr, 2, Ax, Atr, true);   __syncthreads();
    zprod(Ax, 4, Z0, Z1);  powp(Ax, Atr, 4, Pw, Pwtr, true);   __syncthreads();
    zprod(Pw, 8, Z1, Z0);  powp(Pw, Pwtr, 8, Ax, Atr, true);   __syncthreads();
    zprod(Ax, 16, Z0, Z1); powp(Ax, Atr, 16, Pw, Pwtr, false); __syncthreads();
    zprod(Pw, 32, Z1, Z0);
    __syncthreads();

    {
        #pragma unroll
        for (int i = 0; i < 2; ++i) {
            int idx = i * 512 + tid;
            int row = idx >> 3, seg = idx & 7;
            const unsigned short* src = (row < 64) ? (qc + (size_t)row * 64 + seg * 8)
                                                   : (kc + (size_t)(row - 64) * 64 + seg * 8);
            *(ushort8*)&Z1[row * PB + seg * 8] = *(const ushort8*)src;
        }
    }
    __syncthreads();

    {
        short8 qa0 = *(const short8*)&Z1[(16 * mw + lr) * PB + lk];
        short8 qa1 = *(const short8*)&Z1[(16 * mw + lr) * PB + 32 + lk];
        #pragma unroll
        for (int ni = 0; ni < 2; ++ni) {
            int n = nh * 2 + ni;
            short8 kb0 = *(const short8*)&Z1[(64 + 16 * n + lr) * PB + lk];
            short8 kb1 = *(const short8*)&Z1[(64 + 16 * n + lr) * PB + 32 + lk];
            f32x4 a = {};
            a = __builtin_amdgcn_mfma_f32_16x16x32_bf16(qa0, kb0, a, 0, 0, 0);
            a = __builtin_amdgcn_mfma_f32_16x16x32_bf16(qa1, kb1, a, 0, 0, 0);
            #pragma unroll
            for (int j = 0; j < 4; ++j) {
                int tt = 16 * mw + rb + j, s = 16 * n + lr;
                Ax[tt * PB + s] = (s <= tt) ? f2bf(a[j]) : (unsigned short)0;
            }
        }
        ushort8 kv;
        #pragma unroll
        for (int j = 0; j < 8; ++j)
            kv[j] = Z1[(64 + w * 8 + j) * PB + l];
        *(ushort8*)&Pwtr[l * PB + w * 8] = kv;
    }
    __syncthreads();

    {
        unsigned short* tb = tiles + ((size_t)bh * 16 + c) * 12288;
        short8 pA0 = ldb(Ax, mw, 0), pA1 = ldb(Ax, mw, 1);
        short8 zA0 = ldb(Z0, mw, 0), zA1 = ldb(Z0, mw, 1);
        short8 kt0 = ldb(Pwtr, mw, 0), kt1 = ldb(Pwtr, mw, 1);
        #pragma unroll
        for (int ni = 0; ni < 2; ++ni) {
            int n = nh * 2 + ni;
            f32x4 aN = {};
            aN = __builtin_amdgcn_mfma_f32_16x16x32_bf16(zA0, ldb(Pwtr, n, 0), aN, 0, 0, 0);
            aN = __builtin_amdgcn_mfma_f32_16x16x32_bf16(zA1, ldb(Pwtr, n, 1), aN, 0, 0, 0);
            f32x4 aM = {};
            aM = __builtin_amdgcn_mfma_f32_16x16x32_bf16(kt0, ldb(Z0, 4 + n, 0), aM, 0, 0, 0);
            aM = __builtin_amdgcn_mfma_f32_16x16x32_bf16(kt1, ldb(Z0, 4 + n, 1), aM, 0, 0, 0);
            f32x4 aG;
            #pragma unroll
            for (int j = 0; j < 4; ++j) aG[j] = bf2f(Z1[(16 * mw + rb + j) * PB + 16 * n + lr]);
            aG = __builtin_amdgcn_mfma_f32_16x16x32_bf16(pA0, ldb(Z0, 4 + n, 0), aG, 0, 0, 0);
            aG = __builtin_amdgcn_mfma_f32_16x16x32_bf16(pA1, ldb(Z0, 4 + n, 1), aG, 0, 0, 0);
            f32x4 aP = {};
            aP = __builtin_amdgcn_mfma_f32_16x16x32_bf16(pA0, ldb(Z0, n, 0), aP, 0, 0, 0);
            aP = __builtin_amdgcn_mfma_f32_16x16x32_bf16(pA1, ldb(Z0, n, 1), aP, 0, 0, 0);
            #pragma unroll
            for (int j = 0; j < 4; ++j) {
                int r = 16 * mw + rb + j, cl = 16 * n + lr;
                tb[r * 64 + cl]        = f2bf(aM[j]);
                tb[4096 + r * 64 + cl] = f2bf(aG[j]);
                tb[8192 + r * 64 + cl] = f2bf(aN[j]);
                outs[((size_t)(c0 + r) * BSZ + b) * 512 + h * 64 + cl] = f2bf(aP[j]);
            }
        }
    }
}

// ---------------- phase 2a: W-only scan with register prefetch; stores bf16 W checkpoints ----------------
__global__ __launch_bounds__(256) void fwscan_w(const unsigned short* __restrict__ tiles,
                                                unsigned short* __restrict__ wchk) {
    __shared__ float Wf[64 * 68];
    const int bh = blockIdx.x;
    const int tid = threadIdx.x;
    const int w = tid >> 6, l = tid & 63;
    const int lr = l & 15, lk = (l >> 4) << 3, rb = (l >> 4) << 2;
    const int cr = l >> 3, cc8 = (l & 7) * 8;
    #pragma unroll
    for (int j = 0; j < 16; ++j) Wf[(16 * w + j) * 68 + l] = 0.f;

    const unsigned short* tb0 = tiles + (size_t)bh * 16 * 12288;
    unsigned short* wc0 = wchk + (size_t)bh * 16 * 4096;

    auto loadc = [&](short8 (&MT)[4][2], unsigned short (&NV)[4][4], int c) {
        const unsigned short* tb = tb0 + (size_t)c * 12288;
        #pragma unroll
        for (int n = 0; n < 4; ++n) {
            MT[n][0] = *(const short8*)(tb + (size_t)(16 * n + lr) * 64 + lk);
            MT[n][1] = *(const short8*)(tb + (size_t)(16 * n + lr) * 64 + 32 + lk);
            #pragma unroll
            for (int j = 0; j < 4; ++j)
                NV[n][j] = tb[8192 + (size_t)(16 * w + rb + j) * 64 + 16 * n + lr];
        }
    };
    auto stepc = [&](short8 (&MT)[4][2], unsigned short (&NV)[4][4], int c) {
        #pragma unroll
        for (int half = 0; half < 2; ++half) {
            int row = 16 * w + half * 8 + cr;
            const float* p = &Wf[row * 68 + cc8];
            f32x4 x0 = *(const f32x4*)p, x1 = *(const f32x4*)(p + 4);
            ushort8 o;
            #pragma unroll
            for (int j = 0; j < 4; ++j) { o[j] = f2bf(x0[j]); o[4 + j] = f2bf(x1[j]); }
            *(ushort8*)(wc0 + (size_t)c * 4096 + row * 64 + cc8) = o;
        }
        short8 wf0, wf1;
        {
            const float* p0 = &Wf[(16 * w + lr) * 68 + lk];
            f32x4 a0 = *(const f32x4*)p0, b0 = *(const f32x4*)(p0 + 4);
            f32x4 a1 = *(const f32x4*)(p0 + 32), b1 = *(const f32x4*)(p0 + 36);
            #pragma unroll
            for (int j = 0; j < 4; ++j) {
                wf0[j] = (short)f2bf(a0[j]); wf0[4 + j] = (short)f2bf(b0[j]);
                wf1[j] = (short)f2bf(a1[j]); wf1[4 + j] = (short)f2bf(b1[j]);
            }
        }
        #pragma unroll
        for (int n = 0; n < 4; ++n) {
            f32x4 a;
            #pragma unroll
            for (int j = 0; j < 4; ++j)
                a[j] = Wf[(16 * w + rb + j) * 68 + 16 * n + lr] + bf2f(NV[n][j]);
            a = __builtin_amdgcn_mfma_f32_16x16x32_bf16(wf0, MT[n][0], a, 0, 0, 0);
            a = __builtin_amdgcn_mfma_f32_16x16x32_bf16(wf1, MT[n][1], a, 0, 0, 0);
            #pragma unroll
            for (int j = 0; j < 4; ++j) Wf[(16 * w + rb + j) * 68 + 16 * n + lr] = a[j];
        }
    };

    short8 mtA[4][2], mtB[4][2];
    unsigned short nvA[4][4], nvB[4][4];
    loadc(mtA, nvA, 0);
    #pragma unroll 1
    for (int cc = 0; cc < 8; ++cc) {
        int c = 2 * cc;
        if (c + 1 < 16) loadc(mtB, nvB, c + 1);
        stepc(mtA, nvA, c);
        if (c + 2 < 16) loadc(mtA, nvA, c + 2);
        stepc(mtB, nvB, c + 1);
    }
}

// ---------------- phase 2b: O finalize, parallel over (chunk 1..15, bh) ----------------
__global__ __launch_bounds__(256) void fw_o(const unsigned short* __restrict__ tiles,
                                            const unsigned short* __restrict__ wchk,
                                            unsigned short* __restrict__ outs) {
    __shared__ unsigned short Ot[64 * 72];
    const int c = blockIdx.x + 1;
    const int bh = blockIdx.y;
    const int b = bh >> 3, h = bh & 7;
    const int c0 = c * 64;
    const int tid = threadIdx.x;
    const int w = tid >> 6, l = tid & 63;
    const int lr = l & 15, lk = (l >> 4) << 3, rb = (l >> 4) << 2;
    const unsigned short* G  = tiles + ((size_t)bh * 16 + c) * 12288 + 4096;
    const unsigned short* W0 = wchk + ((size_t)bh * 16 + c) * 4096;

    #pragma unroll
    for (int i = 0; i < 2; ++i) {
        int idx = i * 256 + tid;
        int t = idx >> 3, d0 = (idx & 7) * 8;
        *(ushort8*)&Ot[t * 72 + d0] =
            *(const ushort8*)(outs + ((size_t)(c0 + t) * BSZ + b) * 512 + h * 64 + d0);
    }
    __syncthreads();

    short8 g0 = *(const short8*)(G + (size_t)(16 * w + lr) * 64 + lk);
    short8 g1 = *(const short8*)(G + (size_t)(16 * w + lr) * 64 + 32 + lk);
    #pragma unroll
    for (int n = 0; n < 4; ++n) {
        short8 wf0 = *(const short8*)(W0 + (size_t)(16 * n + lr) * 64 + lk);
        short8 wf1 = *(const short8*)(W0 + (size_t)(16 * n + lr) * 64 + 32 + lk);
        f32x4 a;
        #pragma unroll
        for (int j = 0; j < 4; ++j) a[j] = bf2f(Ot[(16 * w + rb + j) * 72 + 16 * n + lr]);
        a = __builtin_amdgcn_mfma_f32_16x16x32_bf16(g0, wf0, a, 0, 0, 0);
        a = __builtin_amdgcn_mfma_f32_16x16x32_bf16(g1, wf1, a, 0, 0, 0);
        #pragma unroll
        for (int j = 0; j < 4; ++j) Ot[(16 * w + rb + j) * 72 + 16 * n + lr] = f2bf(a[j]);
    }
    __syncthreads();

    #pragma unroll
    for (int i = 0; i < 2; ++i) {
        int idx = i * 256 + tid;
        int t = idx >> 3, d0 = (idx & 7) * 8;
        *(ushort8*)(outs + ((size_t)(c0 + t) * BSZ + b) * 512 + h * 64 + d0) =
            *(const ushort8*)&Ot[t * 72 + d0];
    }
}

// ---------------- launch ----------------
extern "C" void kernel_launch(void* const* d_in, const int* in_sizes, int n_in,
                              void* d_out, int out_size, void* d_ws, size_t ws_size,
                              hipStream_t stream) {
    const float* x      = (const float*)d_in[0];
    const float* g      = (const float*)d_in[1];
    const float* be     = (const float*)d_in[2];
    const float* w_slow = (const float*)d_in[3];
    const float* w_out  = (const float*)d_in[4];
    float* out = (float*)d_out;
    char* ws = (char*)d_ws;

    unsigned short* h    = (unsigned short*)(ws);
    unsigned short* outs = (unsigned short*)(ws);                 // alias h
    unsigned short* qn   = (unsigned short*)(ws + 33554432);
    unsigned short* wchk = (unsigned short*)(ws + 33554432);      // alias qn (dead after fwtiles)
    unsigned short* kn   = (unsigned short*)(ws + 67108864);
    unsigned short* vn   = (unsigned short*)(ws + 100663296);
    float*          bet  = (float*)         (ws + 134217728);
    unsigned short* wsT  = (unsigned short*)(ws + 135266304);     // 1792*512*2
    unsigned short* woT  = (unsigned short*)(ws + 137101312);
    unsigned short* tiles= (unsigned short*)(ws + 137625600);

    if (ws_size < 238288896) return;

    ln_kernel<<<8192, 256, 0, stream>>>(x, g, be, h);
    cvt_wslow2<<<dim3(8, 25), 256, 0, stream>>>(w_slow, wsT);
    cvt_wout<<<dim3(8, 8), 256, 0, stream>>>(w_out, woT);
    gemm_qkv<<<dim3(7, MROWS / 256), 512, 0, stream>>>(h, wsT, qn, kn, vn, bet);
    fwtiles<<<BSZ * H_ * 16, 512, 0, stream>>>(qn, kn, vn, bet, tiles, outs);
    fwscan_w<<<BSZ * H_, 256, 0, stream>>>(tiles, wchk);
    fw_o<<<dim3(15, BSZ * H_), 256, 0, stream>>>(tiles, wchk, outs);
    gemm_out<<<dim3(2, MROWS / 256), 512, 0, stream>>>(outs, woT, x, out);
}